// Round 12
// baseline (1115.964 us; speedup 1.0000x reference)
//
#include <hip/hip_runtime.h>

// GAT node regressor: 3 GAT layers (HID=64, 4 heads x 16) + linear head.
// CSR-by-dst via bucketed counting sort, per-node ranges PADDED to x4 (pads
// -> phantom node n: als[n]=-1e30 so pe==0; fp16 xh row n zeroed).
// Features stored once in fp16 (exact bf16 hi/lo re-split on GEMM input).
// R11 lesson: hipLaunchCooperativeKernel is silently dropped under graph
// capture (output stayed zeroed). This round: the tail chain
// agg0->mg1->agg1->mg2->agg2 is ONE REGULAR kernel (k_tail, 1024 blocks)
// with a HAND-ROLLED grid barrier: monotonic agent-scope atomic counter,
// release-add + acquire-spin (invalidates stale per-XCD L2) + syncthreads.
// Co-residency guaranteed: __launch_bounds__(256,4) -> VGPR<=128 -> 4
// blocks/CU x 256 CU = 1024 = grid, so the barrier cannot deadlock.
// Counter zeroed in k_prep every replay; monotonic targets survive rocprof
// dispatch-replay. Layer-0 GEMM overlapped with CSR build via k_mix1/k_mix2.

#define NBMAX 512    // max dst buckets (dst>>8); N=100K -> 391
#define SCHUNK 4096  // edges per bscatter block
#define BCAP 8192    // per-bucket LDS capacity in bfinal (avg 4096+pads)
#define PADSLACK 768 // max padding per bucket = 256 nodes * 3 slots
#define NBH 256      // bhist role blocks inside k_prep
#define TGRID 1024   // k_tail grid (= 4 blocks/CU x 256 CU, all resident)

typedef __attribute__((ext_vector_type(8))) short bf16x8;
typedef __attribute__((ext_vector_type(4))) float f32x4;
typedef _Float16 half_t;
typedef __attribute__((ext_vector_type(8))) _Float16 half8;

__device__ inline unsigned short bf16_rtn(float x) {
    union { float f; unsigned u; } a; a.f = x;
    return (unsigned short)((a.u + 0x7FFFu + ((a.u >> 16) & 1u)) >> 16);
}
__device__ inline float bf16_to_f(unsigned short s) {
    union { unsigned u; float f; } b; b.u = ((unsigned)s) << 16;
    return b.f;
}

// ---- fused W-prep + phantom init + gbar reset + dst histogram
// (bhist pre-zeroed by hipMemsetAsync): blocks 0-7 wprep, 8 init, 9.. bhist ----
__global__ __launch_bounds__(256) void k_prep(const float* __restrict__ w0, const float* __restrict__ w1,
                                              const float* __restrict__ w2,
                                              unsigned short* __restrict__ p0h, unsigned short* __restrict__ p0l,
                                              unsigned short* __restrict__ p1h, unsigned short* __restrict__ p1l,
                                              unsigned short* __restrict__ p2h, unsigned short* __restrict__ p2l,
                                              int* __restrict__ bhist, const int* __restrict__ dst, int e,
                                              float* __restrict__ als, half_t* __restrict__ xh16,
                                              int* __restrict__ gbar, int n) {
    __shared__ unsigned int h[NBMAX];
    int bid = blockIdx.x, t = threadIdx.x;
    if (bid == 8) {  // phantom node init + barrier counter reset
        if (t < 4) als[(size_t)n * 4 + t] = -1e30f;
        if (t < 64) xh16[(size_t)n * 64 + t] = (half_t)0.f;
        if (t == 64) *gbar = 0;
        return;
    }
    if (bid >= 9) {  // bhist role (bhist zeroed via memset)
        int bb = bid - 9;
        h[t] = 0;
        h[t + 256] = 0;
        __syncthreads();
        for (int i = bb * 256 + t; i < e; i += NBH * 256)
            atomicAdd(&h[dst[i] >> 8], 1u);
        __syncthreads();
        if (h[t]) atomicAdd(&bhist[t], (int)h[t]);
        if (h[t + 256]) atomicAdd(&bhist[t + 256], (int)h[t + 256]);
        return;
    }
    int g = bid * 256 + t;
    const float* W;
    unsigned short *ph, *pl;
    int idx;
    if (g < 1024) { W = w0; ph = p0h; pl = p0l; idx = g; }          // D=128: ko 0..15
    else if (g < 1536) { W = w1; ph = p1h; pl = p1l; idx = g - 1024; }  // D=64: ko 0..7
    else if (g < 2048) { W = w2; ph = p2h; pl = p2l; idx = g - 1536; }
    else return;
    int ko = idx >> 6, nn = idx & 63;
#pragma unroll
    for (int j = 0; j < 8; ++j) {
        float w = W[(size_t)(ko * 8 + j) * 64 + nn];
        unsigned short hb = bf16_rtn(w);
        ph[(size_t)idx * 8 + j] = hb;
        pl[(size_t)idx * 8 + j] = bf16_rtn(w - bf16_to_f(hb));
    }
}

__global__ __launch_bounds__(512) void k_bscan(const int* __restrict__ bhist, int* __restrict__ boffs,
                                               int* __restrict__ bfill, int nb, int e) {
    __shared__ int s[NBMAX];
    int t = threadIdx.x;
    int v = (t < nb) ? bhist[t] : 0;
    s[t] = v;
    __syncthreads();
    for (int o = 1; o < 512; o <<= 1) {
        int add = (t >= o) ? s[t - o] : 0;
        __syncthreads();
        s[t] += add;
        __syncthreads();
    }
    boffs[t] = s[t] - v;  // exclusive
    if (t == 511) boffs[512] = s[511];
    bfill[t] = 0;
}

// ---- mgemm wave body: 16 nodes x 64 cols, fused logits + softmax shift.
// HALF_IN: A rows are fp16 (exact under bf16 hi/lo re-split). ----
template <int D_IN, bool HALF_IN>
__device__ __forceinline__ void mgemm_wave(const void* __restrict__ hv,
                                           const unsigned short* __restrict__ wph,
                                           const unsigned short* __restrict__ wpl,
                                           const float* __restrict__ asrc, const float* __restrict__ adst,
                                           half_t* __restrict__ xh16, float* __restrict__ als,
                                           float* __restrict__ ald, float* __restrict__ mvec,
                                           int m0, int lane, int n) {
    int quad = lane >> 4, l16 = lane & 15;
    int node_a = m0 + l16;
    int mm = min(node_a, n - 1);

    f32x4 acc[4];
#pragma unroll
    for (int i = 0; i < 4; ++i) acc[i] = (f32x4){0.f, 0.f, 0.f, 0.f};

    constexpr int KSTEPS = D_IN / 32;
#pragma unroll
    for (int s = 0; s < KSTEPS; ++s) {
        float av[8];
        if constexpr (HALF_IN) {
            const half_t* hrow = (const half_t*)hv + (size_t)mm * D_IN + quad * 8;
            half8 hvv = *(const half8*)(hrow + s * 32);
#pragma unroll
            for (int j = 0; j < 8; ++j) av[j] = (float)hvv[j];
        } else {
            const float* hrow = (const float*)hv + (size_t)mm * D_IN + quad * 8;
            float4 a0 = *(const float4*)(hrow + s * 32);
            float4 a1 = *(const float4*)(hrow + s * 32 + 4);
            av[0] = a0.x; av[1] = a0.y; av[2] = a0.z; av[3] = a0.w;
            av[4] = a1.x; av[5] = a1.y; av[6] = a1.z; av[7] = a1.w;
        }
        bf16x8 ahi, alo;
#pragma unroll
        for (int j = 0; j < 8; ++j) {
            unsigned short hb = bf16_rtn(av[j]);
            ahi[j] = (short)hb;
            alo[j] = (short)bf16_rtn(av[j] - bf16_to_f(hb));
        }
        const unsigned short* bbase = wph + ((size_t)((s * 4 + quad) * 64 + l16)) * 8;
        const unsigned short* bbasel = wpl + ((size_t)((s * 4 + quad) * 64 + l16)) * 8;
#pragma unroll
        for (int nt = 0; nt < 4; ++nt) {
            bf16x8 bhi = *(const bf16x8*)(bbase + (size_t)nt * 16 * 8);
            bf16x8 blo = *(const bf16x8*)(bbasel + (size_t)nt * 16 * 8);
            acc[nt] = __builtin_amdgcn_mfma_f32_16x16x32_bf16(ahi, bhi, acc[nt], 0, 0, 0);
            acc[nt] = __builtin_amdgcn_mfma_f32_16x16x32_bf16(ahi, blo, acc[nt], 0, 0, 0);
            acc[nt] = __builtin_amdgcn_mfma_f32_16x16x32_bf16(alo, bhi, acc[nt], 0, 0, 0);
        }
    }
#pragma unroll
    for (int nt = 0; nt < 4; ++nt) {
        float as_l = asrc[nt * 16 + l16];
        float ad_l = adst[nt * 16 + l16];
#pragma unroll
        for (int r = 0; r < 4; ++r) {
            int node = m0 + quad * 4 + r;
            float c = acc[nt][r];
            if (node < n) xh16[(size_t)node * 64 + nt * 16 + l16] = (half_t)c;
            float ps = c * as_l, pd = c * ad_l;
            ps += __shfl_xor(ps, 1, 64); pd += __shfl_xor(pd, 1, 64);
            ps += __shfl_xor(ps, 2, 64); pd += __shfl_xor(pd, 2, 64);
            ps += __shfl_xor(ps, 4, 64); pd += __shfl_xor(pd, 4, 64);
            ps += __shfl_xor(ps, 8, 64); pd += __shfl_xor(pd, 8, 64);
            if (l16 == 0 && node < n) {
                als[node * 4 + nt] = ps;
                ald[node * 4 + nt] = pd;
                float sm = ps + pd;
                mvec[node * 4 + nt] = sm >= 0.f ? sm : 0.2f * sm;
            }
        }
    }
}

// ---- k_mix1: bscatter (blocks [0,sb)) || layer-0 GEMM half 1 (8 waves) ----
__global__ __launch_bounds__(512) void k_mix1(const int* __restrict__ src, const int* __restrict__ dst,
                                              const int* __restrict__ boffs, int* __restrict__ bfill,
                                              unsigned int* __restrict__ edata, int e, int sb,
                                              const float* __restrict__ x,
                                              const unsigned short* __restrict__ p0h,
                                              const unsigned short* __restrict__ p0l,
                                              const float* __restrict__ asrc, const float* __restrict__ adst,
                                              half_t* __restrict__ xh16, float* __restrict__ als,
                                              float* __restrict__ ald, float* __restrict__ mvec, int n) {
    __shared__ unsigned int hist[NBMAX];
    __shared__ unsigned int loc[NBMAX];
    __shared__ int gbase[NBMAX];
    __shared__ unsigned int stmp[NBMAX];
    __shared__ unsigned int sortbuf[SCHUNK];
    __shared__ int posbuf[SCHUNK];
    int t = threadIdx.x;
    if (blockIdx.x >= sb) {  // mgemm role
        int mblk = blockIdx.x - sb;
        int m0 = mblk * 128 + (t >> 6) * 16;
        mgemm_wave<128, false>(x, p0h, p0l, asrc, adst, xh16, als, ald, mvec, m0, t & 63, n);
        return;
    }
    int i0 = blockIdx.x * SCHUNK;
    int cnt = min(SCHUNK, e - i0);
    hist[t] = 0;
    __syncthreads();
    for (int j = t; j < cnt; j += 512) atomicAdd(&hist[dst[i0 + j] >> 8], 1u);
    __syncthreads();
    unsigned int v = hist[t];
    stmp[t] = v;
    __syncthreads();
    for (int o = 1; o < 512; o <<= 1) {
        unsigned int add = (t >= o) ? stmp[t - o] : 0;
        __syncthreads();
        stmp[t] += add;
        __syncthreads();
    }
    loc[t] = stmp[t] - v;
    int gb = 0;
    if (v > 0) gb = atomicAdd(&bfill[t], (int)v);  // reserve contiguous run in bucket t
    gbase[t] = boffs[t] + gb - (int)loc[t];
    hist[t] = loc[t];  // cursor
    __syncthreads();
    for (int j = t; j < cnt; j += 512) {
        int d = dst[i0 + j];
        int s = src[i0 + j];
        int b = d >> 8;
        unsigned int p = atomicAdd(&hist[b], 1u);
        sortbuf[p] = (unsigned int)s | ((unsigned int)(d & 255) << 24);
        posbuf[p] = gbase[b] + (int)p;
    }
    __syncthreads();
    for (int j = t; j < cnt; j += 512) edata[posbuf[j]] = sortbuf[j];
}

// ---- k_mix2: bfinal (blocks [0,nb)) || layer-0 GEMM half 2 ----
__global__ __launch_bounds__(512) void k_mix2(const unsigned int* __restrict__ edata,
                                              const int* __restrict__ boffs, int* __restrict__ poffs,
                                              int* __restrict__ pend, int* __restrict__ ssrc,
                                              int n, int nb, int mg1,
                                              const float* __restrict__ x,
                                              const unsigned short* __restrict__ p0h,
                                              const unsigned short* __restrict__ p0l,
                                              const float* __restrict__ asrc, const float* __restrict__ adst,
                                              half_t* __restrict__ xh16, float* __restrict__ als,
                                              float* __restrict__ ald, float* __restrict__ mvec) {
    __shared__ unsigned int hist[256];
    __shared__ unsigned int stmp[256];
    __shared__ unsigned int loc2[256];
    __shared__ unsigned int srcbuf[BCAP];
    int t = threadIdx.x;
    if (blockIdx.x >= nb) {  // mgemm role: second half of nodes
        int mblk = mg1 + (blockIdx.x - nb);
        int m0 = mblk * 128 + (t >> 6) * 16;
        mgemm_wave<128, false>(x, p0h, p0l, asrc, adst, xh16, als, ald, mvec, m0, t & 63, n);
        return;
    }
    int b = blockIdx.x;
    int e0 = boffs[b], e1 = boffs[b + 1];
    int cnt = e1 - e0;
    int pb = e0 + b * PADSLACK;
    if (t < 256) hist[t] = 0;
    __syncthreads();
    for (int j = t; j < cnt; j += 512) atomicAdd(&hist[edata[e0 + j] >> 24], 1u);
    __syncthreads();
    unsigned int v = 0, v4 = 0;
    if (t < 256) {
        v = hist[t];
        v4 = (v + 3u) & ~3u;
        stmp[t] = v4;
    }
    __syncthreads();
    for (int o = 1; o < 256; o <<= 1) {
        unsigned int add = 0;
        if (t < 256 && t >= o) add = stmp[t - o];
        __syncthreads();
        if (t < 256) stmp[t] += add;
        __syncthreads();
    }
    int ptot = (int)stmp[255];
    if (t < 256) {
        loc2[t] = stmp[t] - v4;  // padded exclusive offset
        int node = b * 256 + t;
        if (node < n) {
            poffs[node] = pb + (int)loc2[t];
            pend[node] = pb + (int)(loc2[t] + v4);
        }
        hist[t] = loc2[t];  // cursor
    }
    __syncthreads();
    if (cnt + PADSLACK <= BCAP) {
        for (int j = t; j < cnt; j += 512) {
            unsigned int p = edata[e0 + j];
            unsigned int pos = atomicAdd(&hist[p >> 24], 1u);
            srcbuf[pos] = p & 0xFFFFFFu;
        }
        if (t < 256)
            for (unsigned int k = v; k < v4; ++k) srcbuf[loc2[t] + k] = (unsigned int)n;  // pads
        __syncthreads();
        for (int j = t; j < ptot; j += 512) ssrc[pb + j] = (int)srcbuf[j];
    } else {  // safety fallback (never hit for Poisson(4096) buckets)
        for (int j = t; j < cnt; j += 512) {
            unsigned int p = edata[e0 + j];
            unsigned int pos = atomicAdd(&hist[p >> 24], 1u);
            ssrc[pb + (int)pos] = (int)(p & 0xFFFFFFu);
        }
        if (t < 256)
            for (unsigned int k = v; k < v4; ++k) ssrc[pb + (int)(loc2[t] + k)] = n;
    }
}

__device__ inline float4 lrelu4(float4 v) {
    float4 r;
    r.x = v.x >= 0.f ? v.x : 0.2f * v.x;
    r.y = v.y >= 0.f ? v.y : 0.2f * v.y;
    r.z = v.z >= 0.f ? v.z : 0.2f * v.z;
    r.w = v.w >= 0.f ? v.w : 0.2f * v.w;
    return r;
}

// Aligned accumulate over [LO,HI) within chunk starting at s0; fp16 row
// gathers (128B/edge), two fmac chains per node.
#define ACCUM(LO, HI, ACCA, ACCB, ZS)                                           \
    {                                                                           \
        int g_ = ((LO) - s0) >> 2, gb_ = ((HI) - s0) >> 2;                      \
        for (; g_ + 4 <= gb_; g_ += 4) {                                        \
            int4 uu0 = *(const int4*)&ub[g_ * 4];                               \
            int4 uu1 = *(const int4*)&ub[g_ * 4 + 4];                           \
            int4 uu2 = *(const int4*)&ub[g_ * 4 + 8];                           \
            int4 uu3 = *(const int4*)&ub[g_ * 4 + 12];                          \
            float4 pp0 = *(const float4*)&per[g_ * 4];                          \
            float4 pp1 = *(const float4*)&per[g_ * 4 + 4];                      \
            float4 pp2 = *(const float4*)&per[g_ * 4 + 8];                      \
            float4 pp3 = *(const float4*)&per[g_ * 4 + 12];                     \
            float x0 = (float)*(const half_t*)(xl + (size_t)(unsigned)uu0.x);   \
            float x1 = (float)*(const half_t*)(xl + (size_t)(unsigned)uu0.y);   \
            float x2 = (float)*(const half_t*)(xl + (size_t)(unsigned)uu0.z);   \
            float x3 = (float)*(const half_t*)(xl + (size_t)(unsigned)uu0.w);   \
            float x4 = (float)*(const half_t*)(xl + (size_t)(unsigned)uu1.x);   \
            float x5 = (float)*(const half_t*)(xl + (size_t)(unsigned)uu1.y);   \
            float x6 = (float)*(const half_t*)(xl + (size_t)(unsigned)uu1.z);   \
            float x7 = (float)*(const half_t*)(xl + (size_t)(unsigned)uu1.w);   \
            float x8 = (float)*(const half_t*)(xl + (size_t)(unsigned)uu2.x);   \
            float x9 = (float)*(const half_t*)(xl + (size_t)(unsigned)uu2.y);   \
            float xa = (float)*(const half_t*)(xl + (size_t)(unsigned)uu2.z);   \
            float xb = (float)*(const half_t*)(xl + (size_t)(unsigned)uu2.w);   \
            float xc = (float)*(const half_t*)(xl + (size_t)(unsigned)uu3.x);   \
            float xd = (float)*(const half_t*)(xl + (size_t)(unsigned)uu3.y);   \
            float xe = (float)*(const half_t*)(xl + (size_t)(unsigned)uu3.z);   \
            float xf = (float)*(const half_t*)(xl + (size_t)(unsigned)uu3.w);   \
            ZS += pp0.x + pp0.y + pp0.z + pp0.w;                                \
            ZS += pp1.x + pp1.y + pp1.z + pp1.w;                                \
            ZS += pp2.x + pp2.y + pp2.z + pp2.w;                                \
            ZS += pp3.x + pp3.y + pp3.z + pp3.w;                                \
            ACCA += pp0.x * x0; ACCB += pp0.y * x1;                             \
            ACCA += pp0.z * x2; ACCB += pp0.w * x3;                             \
            ACCA += pp1.x * x4; ACCB += pp1.y * x5;                             \
            ACCA += pp1.z * x6; ACCB += pp1.w * x7;                             \
            ACCA += pp2.x * x8; ACCB += pp2.y * x9;                             \
            ACCA += pp2.z * xa; ACCB += pp2.w * xb;                             \
            ACCA += pp3.x * xc; ACCB += pp3.y * xd;                             \
            ACCA += pp3.z * xe; ACCB += pp3.w * xf;                             \
        }                                                                       \
        for (; g_ < gb_; ++g_) {                                                \
            int4 uu = *(const int4*)&ub[g_ * 4];                                \
            float4 pp = *(const float4*)&per[g_ * 4];                           \
            float x0 = (float)*(const half_t*)(xl + (size_t)(unsigned)uu.x);    \
            float x1 = (float)*(const half_t*)(xl + (size_t)(unsigned)uu.y);    \
            float x2 = (float)*(const half_t*)(xl + (size_t)(unsigned)uu.z);    \
            float x3 = (float)*(const half_t*)(xl + (size_t)(unsigned)uu.w);    \
            ZS += pp.x + pp.y + pp.z + pp.w;                                    \
            ACCA += pp.x * x0; ACCB += pp.y * x1;                               \
            ACCA += pp.z * x2; ACCB += pp.w * x3;                               \
        }                                                                       \
    }

// agg body for one virtual block vb (4 waves x 4 nodes). Same-wave LDS only,
// no __syncthreads -> safe per-wave early return.
__device__ __forceinline__ void agg_body(int vb, const half_t* __restrict__ xh16,
                                         const float* __restrict__ als, const float* __restrict__ ald,
                                         const float* __restrict__ mvec,
                                         const int* __restrict__ poffs, const int* __restrict__ pend,
                                         const int* __restrict__ ssrc,
                                         const float* __restrict__ bias, half_t* __restrict__ hout,
                                         const float* __restrict__ outw, const float* __restrict__ outb,
                                         float* __restrict__ fout, int n) {
    static __shared__ int s_u[4][64];
    static __shared__ float s_pe[4][4][64];  // [wslot][head][edge]
    int wslot = threadIdx.x >> 6;
    int lane = threadIdx.x & 63;
    int v0 = ((vb << 2) + wslot) << 2;
    if (v0 >= n) return;
    int head = lane >> 4;
    int* ub = s_u[wslot];
    float* per = s_pe[wslot][head];      // read row for my head
    float* pew = &s_pe[wslot][0][lane];  // write base, stride 64 per head

    int vlast = n - 1;
    int last = min(v0 + 3, vlast);
    int4 rr = *(const int4*)(poffs + v0);
    int e3 = pend[last];
    int r0 = rr.x;
    int r1 = (v0 + 1 <= last) ? rr.y : e3;
    int r2 = (v0 + 2 <= last) ? rr.z : e3;
    int r3 = (v0 + 3 <= last) ? rr.w : e3;

    const char* xl = (const char*)(xh16 + lane);  // lane column folded into base
    float acc0a = (float)xh16[((size_t)(unsigned)v0 << 6) + lane];  // self, pe=1
    float acc1a = (float)xh16[((size_t)(unsigned)min(v0 + 1, vlast) << 6) + lane];
    float acc2a = (float)xh16[((size_t)(unsigned)min(v0 + 2, vlast) << 6) + lane];
    float acc3a = (float)xh16[((size_t)(unsigned)min(v0 + 3, vlast) << 6) + lane];
    float acc0b = 0.f, acc1b = 0.f, acc2b = 0.f, acc3b = 0.f;
    float zs0 = 0.f, zs1 = 0.f, zs2 = 0.f, zs3 = 0.f;

    // prefetch chunk 0 (ssrc -> dependent als gather; ald/m by nid)
    int s0 = r0;
    int u_n = n;
    if (s0 < e3) {
        if (lane < e3 - s0) u_n = ssrc[s0 + lane];
    }
    float4 alu_n = *(const float4*)(als + 4 * (size_t)u_n);
    int e_n = s0 + lane;
    int nid_n = min(v0 + (e_n >= r1) + (e_n >= r2) + (e_n >= r3), vlast);
    float4 ald_n = *(const float4*)(ald + 4 * (size_t)nid_n);
    float4 m_n = *(const float4*)(mvec + 4 * (size_t)nid_n);

    while (s0 < e3) {
        int cnt = min(64, e3 - s0);
        float4 e4 = lrelu4(make_float4(alu_n.x + ald_n.x, alu_n.y + ald_n.y,
                                       alu_n.z + ald_n.z, alu_n.w + ald_n.w));
        float4 pe;
        pe.x = __expf(e4.x - m_n.x);
        pe.y = __expf(e4.y - m_n.y);
        pe.z = __expf(e4.z - m_n.z);
        pe.w = __expf(e4.w - m_n.w);
        ub[lane] = u_n << 7;  // fp16 row byte offset; pads point at phantom n
        pew[0] = pe.x;        // transposed stash: bank stride 64 -> 2-way, free
        pew[64] = pe.y;
        pew[128] = pe.z;
        pew[192] = pe.w;
        int s1 = s0 + 64;
        if (s1 < e3) {  // issue next chunk's loads before accumulate
            u_n = n;
            if (lane < e3 - s1) u_n = ssrc[s1 + lane];
            alu_n = *(const float4*)(als + 4 * (size_t)u_n);
            int e1 = s1 + lane;
            int nid1 = min(v0 + (e1 >= r1) + (e1 >= r2) + (e1 >= r3), vlast);
            ald_n = *(const float4*)(ald + 4 * (size_t)nid1);
            m_n = *(const float4*)(mvec + 4 * (size_t)nid1);
        }
        // same-wave LDS RAW (in-order DS unit), no barrier needed
        int lim = s0 + cnt;
        int hi0 = min(r1, lim);
        int lo1 = max(r1, s0), hi1 = min(r2, lim);
        int lo2 = max(r2, s0), hi2 = min(r3, lim);
        int lo3 = max(r3, s0);
        ACCUM(s0, hi0, acc0a, acc0b, zs0);
        ACCUM(lo1, hi1, acc1a, acc1b, zs1);
        ACCUM(lo2, hi2, acc2a, acc2b, zs2);
        ACCUM(lo3, lim, acc3a, acc3b, zs3);
        s0 = s1;
    }

    float bl = bias[lane];
    float o0 = fmaxf((acc0a + acc0b) / (1.f + zs0 + 1e-16f) + bl, 0.f);
    float o1 = fmaxf((acc1a + acc1b) / (1.f + zs1 + 1e-16f) + bl, 0.f);
    float o2 = fmaxf((acc2a + acc2b) / (1.f + zs2 + 1e-16f) + bl, 0.f);
    float o3 = fmaxf((acc3a + acc3b) / (1.f + zs3 + 1e-16f) + bl, 0.f);
    if (outw) {
        float ow = outw[lane];
        float ob = outb[0];
        float t0 = o0 * ow, t1 = o1 * ow, t2 = o2 * ow, t3 = o3 * ow;
#pragma unroll
        for (int d = 32; d; d >>= 1) {
            t0 += __shfl_down(t0, d, 64);
            t1 += __shfl_down(t1, d, 64);
            t2 += __shfl_down(t2, d, 64);
            t3 += __shfl_down(t3, d, 64);
        }
        if (lane == 0) {
            fout[v0] = t0 + ob;
            if (v0 + 1 < n) fout[v0 + 1] = t1 + ob;
            if (v0 + 2 < n) fout[v0 + 2] = t2 + ob;
            if (v0 + 3 < n) fout[v0 + 3] = t3 + ob;
        }
    } else {
        hout[((size_t)v0 << 6) + lane] = (half_t)o0;
        if (v0 + 1 < n) hout[((size_t)(v0 + 1) << 6) + lane] = (half_t)o1;
        if (v0 + 2 < n) hout[((size_t)(v0 + 2) << 6) + lane] = (half_t)o2;
        if (v0 + 3 < n) hout[((size_t)(v0 + 3) << 6) + lane] = (half_t)o3;
    }
}

// Hand-rolled grid barrier: monotonic agent-scope counter. All TGRID blocks
// are resident (launch_bounds cap), so spin cannot deadlock. Release-add
// publishes this block's writes; acquire-load invalidates stale per-XCD L2.
__device__ __forceinline__ void grid_barrier(int* cnt, int phase) {
    __syncthreads();
    if (threadIdx.x == 0) {
        __threadfence();
        __hip_atomic_fetch_add(cnt, 1, __ATOMIC_RELEASE, __HIP_MEMORY_SCOPE_AGENT);
        int target = TGRID * (phase + 1);
        while (__hip_atomic_load(cnt, __ATOMIC_ACQUIRE, __HIP_MEMORY_SCOPE_AGENT) < target)
            __builtin_amdgcn_s_sleep(8);
    }
    __syncthreads();
}

// ---- fused tail: agg0 -> mgemm64(L1) -> agg1 -> mgemm64(L2) -> agg2+head.
// Regular launch (graph-capture-safe). 1024 blocks, all resident.
__global__ __launch_bounds__(256, 4) void k_tail(const half_t* xh16, half_t* hbuf,
                                                 float* als, float* ald, float* mvec,
                                                 const int* poffs, const int* pend, const int* ssrc,
                                                 const float* b0, const float* b1, const float* b2,
                                                 const unsigned short* p1h, const unsigned short* p1l,
                                                 const unsigned short* p2h, const unsigned short* p2l,
                                                 const float* as1, const float* ad1,
                                                 const float* as2, const float* ad2,
                                                 const float* outw, const float* outb,
                                                 float* fout, int* gbar, int n) {
    int nvb = (n + 15) / 16;   // agg virtual blocks
    int ngb = (n + 63) / 64;   // mgemm64 virtual blocks
    int t = threadIdx.x;

    // phase 0: agg layer 0 (xh16 -> hbuf)
    for (int vb = blockIdx.x; vb < nvb; vb += gridDim.x)
        agg_body(vb, xh16, als, ald, mvec, poffs, pend, ssrc, b0, hbuf, nullptr, nullptr, nullptr, n);
    grid_barrier(gbar, 0);
    // phase 1: mgemm64 layer 1 (hbuf -> xh16, als/ald/mvec)
    for (int mb = blockIdx.x; mb < ngb; mb += gridDim.x)
        mgemm_wave<64, true>(hbuf, p1h, p1l, as1, ad1, (half_t*)xh16, als, ald, mvec,
                             mb * 64 + (t >> 6) * 16, t & 63, n);
    grid_barrier(gbar, 1);
    // phase 2: agg layer 1 (xh16 -> hbuf)
    for (int vb = blockIdx.x; vb < nvb; vb += gridDim.x)
        agg_body(vb, xh16, als, ald, mvec, poffs, pend, ssrc, b1, hbuf, nullptr, nullptr, nullptr, n);
    grid_barrier(gbar, 2);
    // phase 3: mgemm64 layer 2
    for (int mb = blockIdx.x; mb < ngb; mb += gridDim.x)
        mgemm_wave<64, true>(hbuf, p2h, p2l, as2, ad2, (half_t*)xh16, als, ald, mvec,
                             mb * 64 + (t >> 6) * 16, t & 63, n);
    grid_barrier(gbar, 3);
    // phase 4: agg layer 2 + fused linear head
    for (int vb = blockIdx.x; vb < nvb; vb += gridDim.x)
        agg_body(vb, xh16, als, ald, mvec, poffs, pend, ssrc, b2, nullptr, outw, outb, fout, n);
}

extern "C" void kernel_launch(void* const* d_in, const int* in_sizes, int n_in,
                              void* d_out, int out_size, void* d_ws, size_t ws_size,
                              hipStream_t stream) {
    const float* x = (const float*)d_in[0];
    const int* ei = (const int*)d_in[1];
    const float* w[3] = {(const float*)d_in[2], (const float*)d_in[6], (const float*)d_in[10]};
    const float* as[3] = {(const float*)d_in[3], (const float*)d_in[7], (const float*)d_in[11]};
    const float* ad[3] = {(const float*)d_in[4], (const float*)d_in[8], (const float*)d_in[12]};
    const float* b[3] = {(const float*)d_in[5], (const float*)d_in[9], (const float*)d_in[13]};
    const float* outw = (const float*)d_in[14];
    const float* outb = (const float*)d_in[15];

    const int N = in_sizes[0] / 128;
    const int E = in_sizes[1] / 2;
    const int* src = ei;
    const int* dst = ei + E;
    const int NB = (N + 255) / 256;           // 391 <= NBMAX
    const int SB = (E + SCHUNK - 1) / SCHUNK; // 391
    const int GB128 = (N + 127) / 128;        // 782
    const int MG1 = (GB128 + 1) / 2;          // 391
    const int MG2 = GB128 - MG1;              // 391

    char* ws = (char*)d_ws;
    auto alloc = [&](size_t bytes) -> void* {
        void* p = (void*)ws;
        ws += (bytes + 255) & ~(size_t)255;
        return p;
    };
    int* bhist = (int*)alloc(NBMAX * 4);
    int* boffs = (int*)alloc((NBMAX + 1) * 4);
    int* bfill = (int*)alloc(NBMAX * 4);
    int* gbar = (int*)alloc(256);
    int* poffs = (int*)alloc((size_t)(N + 8) * 4);
    int* pend = (int*)alloc((size_t)N * 4);
    int* ssrc = (int*)alloc((size_t)(E + NBMAX * PADSLACK + 256) * 4);
    half_t* xh16 = (half_t*)alloc((size_t)(N + 1) * 64 * 2);  // +1: phantom zero row
    half_t* hbuf = (half_t*)alloc((size_t)N * 64 * 2);
    float* als = (float*)alloc((size_t)(N + 1) * 4 * 4);  // +1: phantom -1e30
    float* ald = (float*)alloc((size_t)N * 4 * 4);
    float* mvec = (float*)alloc((size_t)N * 4 * 4);
    unsigned short* p0h = (unsigned short*)alloc(8192 * 2);
    unsigned short* p0l = (unsigned short*)alloc(8192 * 2);
    unsigned short* p1h = (unsigned short*)alloc(4096 * 2);
    unsigned short* p1l = (unsigned short*)alloc(4096 * 2);
    unsigned short* p2h = (unsigned short*)alloc(4096 * 2);
    unsigned short* p2l = (unsigned short*)alloc(4096 * 2);
    // edata (E*4B = 6.4MB) aliases hbuf (N*128B = 12.8MB): hbuf stays dead
    // until k_tail phase 0 writes it, after k_mix2 consumed edata.
    unsigned int* edata = (unsigned int*)hbuf;

    hipMemsetAsync(bhist, 0, NBMAX * 4, stream);  // stream-ordered; capture-safe
    k_prep<<<9 + NBH, 256, 0, stream>>>(w[0], w[1], w[2], p0h, p0l, p1h, p1l, p2h, p2l,
                                        bhist, dst, E, als, xh16, gbar, N);
    k_bscan<<<1, 512, 0, stream>>>(bhist, boffs, bfill, NB, E);
    // CSR scatter || layer-0 GEMM first half (independent workloads)
    k_mix1<<<SB + MG1, 512, 0, stream>>>(src, dst, boffs, bfill, edata, E, SB,
                                         x, p0h, p0l, as[0], ad[0], xh16, als, ald, mvec, N);
    // CSR finalize || layer-0 GEMM second half
    k_mix2<<<NB + MG2, 512, 0, stream>>>(edata, boffs, poffs, pend, ssrc, N, NB, MG1,
                                         x, p0h, p0l, as[0], ad[0], xh16, als, ald, mvec);
    // fused tail: agg0 -> mg1 -> agg1 -> mg2 -> agg2+head (one regular launch)
    k_tail<<<TGRID, 256, 0, stream>>>(xh16, hbuf, als, ald, mvec, poffs, pend, ssrc,
                                      b[0], b[1], b[2], p1h, p1l, p2h, p2l,
                                      as[1], ad[1], as[2], ad[2],
                                      outw, outb, (float*)d_out, gbar, N);
}

// Round 13
// 886.696 us; speedup vs baseline: 1.2586x; 1.2586x over previous
//
#include <hip/hip_runtime.h>

// GAT node regressor: 3 GAT layers (HID=64, 4 heads x 16) + linear head.
// CSR-by-dst via bucketed counting sort, per-node ranges PADDED to x4 (pads
// -> phantom node n: als[n]=-1e30 so pe==0; fp16 xh row n zeroed).
// Features stored once in fp16 (exact bf16 hi/lo re-split on GEMM input).
// Tail chain agg0->mg1->agg1->mg2->agg2 is ONE regular kernel (k_tail, 1024
// blocks, all resident via __launch_bounds__(256,4)) with a hand-rolled grid
// barrier. R12 lesson: an ACQUIRE atomic load in the spin loop poisons the
// caches (agent-scope invalidate per iteration x 1024 blocks -> 986us).
// Fixed: RELAXED spin + s_sleep backoff; ONE threadfence before the signal
// (release) and ONE after the spin exits (acquire). Counter zeroed in k_prep
// each replay; monotonic targets survive rocprof dispatch-replay.
// Layer-0 GEMM overlapped with CSR build via k_mix1/k_mix2.

#define NBMAX 512    // max dst buckets (dst>>8); N=100K -> 391
#define SCHUNK 4096  // edges per bscatter block
#define BCAP 8192    // per-bucket LDS capacity in bfinal (avg 4096+pads)
#define PADSLACK 768 // max padding per bucket = 256 nodes * 3 slots
#define NBH 256      // bhist role blocks inside k_prep
#define TGRID 1024   // k_tail grid (= 4 blocks/CU x 256 CU, all resident)

typedef __attribute__((ext_vector_type(8))) short bf16x8;
typedef __attribute__((ext_vector_type(4))) float f32x4;
typedef _Float16 half_t;
typedef __attribute__((ext_vector_type(8))) _Float16 half8;

__device__ inline unsigned short bf16_rtn(float x) {
    union { float f; unsigned u; } a; a.f = x;
    return (unsigned short)((a.u + 0x7FFFu + ((a.u >> 16) & 1u)) >> 16);
}
__device__ inline float bf16_to_f(unsigned short s) {
    union { unsigned u; float f; } b; b.u = ((unsigned)s) << 16;
    return b.f;
}

// ---- fused W-prep + phantom init + gbar reset + dst histogram
// (bhist pre-zeroed by hipMemsetAsync): blocks 0-7 wprep, 8 init, 9.. bhist ----
__global__ __launch_bounds__(256) void k_prep(const float* __restrict__ w0, const float* __restrict__ w1,
                                              const float* __restrict__ w2,
                                              unsigned short* __restrict__ p0h, unsigned short* __restrict__ p0l,
                                              unsigned short* __restrict__ p1h, unsigned short* __restrict__ p1l,
                                              unsigned short* __restrict__ p2h, unsigned short* __restrict__ p2l,
                                              int* __restrict__ bhist, const int* __restrict__ dst, int e,
                                              float* __restrict__ als, half_t* __restrict__ xh16,
                                              int* __restrict__ gbar, int n) {
    __shared__ unsigned int h[NBMAX];
    int bid = blockIdx.x, t = threadIdx.x;
    if (bid == 8) {  // phantom node init + barrier counter reset
        if (t < 4) als[(size_t)n * 4 + t] = -1e30f;
        if (t < 64) xh16[(size_t)n * 64 + t] = (half_t)0.f;
        if (t == 64) *gbar = 0;
        return;
    }
    if (bid >= 9) {  // bhist role (bhist zeroed via memset)
        int bb = bid - 9;
        h[t] = 0;
        h[t + 256] = 0;
        __syncthreads();
        for (int i = bb * 256 + t; i < e; i += NBH * 256)
            atomicAdd(&h[dst[i] >> 8], 1u);
        __syncthreads();
        if (h[t]) atomicAdd(&bhist[t], (int)h[t]);
        if (h[t + 256]) atomicAdd(&bhist[t + 256], (int)h[t + 256]);
        return;
    }
    int g = bid * 256 + t;
    const float* W;
    unsigned short *ph, *pl;
    int idx;
    if (g < 1024) { W = w0; ph = p0h; pl = p0l; idx = g; }          // D=128: ko 0..15
    else if (g < 1536) { W = w1; ph = p1h; pl = p1l; idx = g - 1024; }  // D=64: ko 0..7
    else if (g < 2048) { W = w2; ph = p2h; pl = p2l; idx = g - 1536; }
    else return;
    int ko = idx >> 6, nn = idx & 63;
#pragma unroll
    for (int j = 0; j < 8; ++j) {
        float w = W[(size_t)(ko * 8 + j) * 64 + nn];
        unsigned short hb = bf16_rtn(w);
        ph[(size_t)idx * 8 + j] = hb;
        pl[(size_t)idx * 8 + j] = bf16_rtn(w - bf16_to_f(hb));
    }
}

__global__ __launch_bounds__(512) void k_bscan(const int* __restrict__ bhist, int* __restrict__ boffs,
                                               int* __restrict__ bfill, int nb, int e) {
    __shared__ int s[NBMAX];
    int t = threadIdx.x;
    int v = (t < nb) ? bhist[t] : 0;
    s[t] = v;
    __syncthreads();
    for (int o = 1; o < 512; o <<= 1) {
        int add = (t >= o) ? s[t - o] : 0;
        __syncthreads();
        s[t] += add;
        __syncthreads();
    }
    boffs[t] = s[t] - v;  // exclusive
    if (t == 511) boffs[512] = s[511];
    bfill[t] = 0;
}

// ---- mgemm wave body: 16 nodes x 64 cols, fused logits + softmax shift.
// HALF_IN: A rows are fp16 (exact under bf16 hi/lo re-split). ----
template <int D_IN, bool HALF_IN>
__device__ __forceinline__ void mgemm_wave(const void* __restrict__ hv,
                                           const unsigned short* __restrict__ wph,
                                           const unsigned short* __restrict__ wpl,
                                           const float* __restrict__ asrc, const float* __restrict__ adst,
                                           half_t* __restrict__ xh16, float* __restrict__ als,
                                           float* __restrict__ ald, float* __restrict__ mvec,
                                           int m0, int lane, int n) {
    int quad = lane >> 4, l16 = lane & 15;
    int node_a = m0 + l16;
    int mm = min(node_a, n - 1);

    f32x4 acc[4];
#pragma unroll
    for (int i = 0; i < 4; ++i) acc[i] = (f32x4){0.f, 0.f, 0.f, 0.f};

    constexpr int KSTEPS = D_IN / 32;
#pragma unroll
    for (int s = 0; s < KSTEPS; ++s) {
        float av[8];
        if constexpr (HALF_IN) {
            const half_t* hrow = (const half_t*)hv + (size_t)mm * D_IN + quad * 8;
            half8 hvv = *(const half8*)(hrow + s * 32);
#pragma unroll
            for (int j = 0; j < 8; ++j) av[j] = (float)hvv[j];
        } else {
            const float* hrow = (const float*)hv + (size_t)mm * D_IN + quad * 8;
            float4 a0 = *(const float4*)(hrow + s * 32);
            float4 a1 = *(const float4*)(hrow + s * 32 + 4);
            av[0] = a0.x; av[1] = a0.y; av[2] = a0.z; av[3] = a0.w;
            av[4] = a1.x; av[5] = a1.y; av[6] = a1.z; av[7] = a1.w;
        }
        bf16x8 ahi, alo;
#pragma unroll
        for (int j = 0; j < 8; ++j) {
            unsigned short hb = bf16_rtn(av[j]);
            ahi[j] = (short)hb;
            alo[j] = (short)bf16_rtn(av[j] - bf16_to_f(hb));
        }
        const unsigned short* bbase = wph + ((size_t)((s * 4 + quad) * 64 + l16)) * 8;
        const unsigned short* bbasel = wpl + ((size_t)((s * 4 + quad) * 64 + l16)) * 8;
#pragma unroll
        for (int nt = 0; nt < 4; ++nt) {
            bf16x8 bhi = *(const bf16x8*)(bbase + (size_t)nt * 16 * 8);
            bf16x8 blo = *(const bf16x8*)(bbasel + (size_t)nt * 16 * 8);
            acc[nt] = __builtin_amdgcn_mfma_f32_16x16x32_bf16(ahi, bhi, acc[nt], 0, 0, 0);
            acc[nt] = __builtin_amdgcn_mfma_f32_16x16x32_bf16(ahi, blo, acc[nt], 0, 0, 0);
            acc[nt] = __builtin_amdgcn_mfma_f32_16x16x32_bf16(alo, bhi, acc[nt], 0, 0, 0);
        }
    }
#pragma unroll
    for (int nt = 0; nt < 4; ++nt) {
        float as_l = asrc[nt * 16 + l16];
        float ad_l = adst[nt * 16 + l16];
#pragma unroll
        for (int r = 0; r < 4; ++r) {
            int node = m0 + quad * 4 + r;
            float c = acc[nt][r];
            if (node < n) xh16[(size_t)node * 64 + nt * 16 + l16] = (half_t)c;
            float ps = c * as_l, pd = c * ad_l;
            ps += __shfl_xor(ps, 1, 64); pd += __shfl_xor(pd, 1, 64);
            ps += __shfl_xor(ps, 2, 64); pd += __shfl_xor(pd, 2, 64);
            ps += __shfl_xor(ps, 4, 64); pd += __shfl_xor(pd, 4, 64);
            ps += __shfl_xor(ps, 8, 64); pd += __shfl_xor(pd, 8, 64);
            if (l16 == 0 && node < n) {
                als[node * 4 + nt] = ps;
                ald[node * 4 + nt] = pd;
                float sm = ps + pd;
                mvec[node * 4 + nt] = sm >= 0.f ? sm : 0.2f * sm;
            }
        }
    }
}

// ---- k_mix1: bscatter (blocks [0,sb)) || layer-0 GEMM half 1 (8 waves) ----
__global__ __launch_bounds__(512) void k_mix1(const int* __restrict__ src, const int* __restrict__ dst,
                                              const int* __restrict__ boffs, int* __restrict__ bfill,
                                              unsigned int* __restrict__ edata, int e, int sb,
                                              const float* __restrict__ x,
                                              const unsigned short* __restrict__ p0h,
                                              const unsigned short* __restrict__ p0l,
                                              const float* __restrict__ asrc, const float* __restrict__ adst,
                                              half_t* __restrict__ xh16, float* __restrict__ als,
                                              float* __restrict__ ald, float* __restrict__ mvec, int n) {
    __shared__ unsigned int hist[NBMAX];
    __shared__ unsigned int loc[NBMAX];
    __shared__ int gbase[NBMAX];
    __shared__ unsigned int stmp[NBMAX];
    __shared__ unsigned int sortbuf[SCHUNK];
    __shared__ int posbuf[SCHUNK];
    int t = threadIdx.x;
    if (blockIdx.x >= sb) {  // mgemm role
        int mblk = blockIdx.x - sb;
        int m0 = mblk * 128 + (t >> 6) * 16;
        mgemm_wave<128, false>(x, p0h, p0l, asrc, adst, xh16, als, ald, mvec, m0, t & 63, n);
        return;
    }
    int i0 = blockIdx.x * SCHUNK;
    int cnt = min(SCHUNK, e - i0);
    hist[t] = 0;
    __syncthreads();
    for (int j = t; j < cnt; j += 512) atomicAdd(&hist[dst[i0 + j] >> 8], 1u);
    __syncthreads();
    unsigned int v = hist[t];
    stmp[t] = v;
    __syncthreads();
    for (int o = 1; o < 512; o <<= 1) {
        unsigned int add = (t >= o) ? stmp[t - o] : 0;
        __syncthreads();
        stmp[t] += add;
        __syncthreads();
    }
    loc[t] = stmp[t] - v;
    int gb = 0;
    if (v > 0) gb = atomicAdd(&bfill[t], (int)v);  // reserve contiguous run in bucket t
    gbase[t] = boffs[t] + gb - (int)loc[t];
    hist[t] = loc[t];  // cursor
    __syncthreads();
    for (int j = t; j < cnt; j += 512) {
        int d = dst[i0 + j];
        int s = src[i0 + j];
        int b = d >> 8;
        unsigned int p = atomicAdd(&hist[b], 1u);
        sortbuf[p] = (unsigned int)s | ((unsigned int)(d & 255) << 24);
        posbuf[p] = gbase[b] + (int)p;
    }
    __syncthreads();
    for (int j = t; j < cnt; j += 512) edata[posbuf[j]] = sortbuf[j];
}

// ---- k_mix2: bfinal (blocks [0,nb)) || layer-0 GEMM half 2 ----
__global__ __launch_bounds__(512) void k_mix2(const unsigned int* __restrict__ edata,
                                              const int* __restrict__ boffs, int* __restrict__ poffs,
                                              int* __restrict__ pend, int* __restrict__ ssrc,
                                              int n, int nb, int mg1,
                                              const float* __restrict__ x,
                                              const unsigned short* __restrict__ p0h,
                                              const unsigned short* __restrict__ p0l,
                                              const float* __restrict__ asrc, const float* __restrict__ adst,
                                              half_t* __restrict__ xh16, float* __restrict__ als,
                                              float* __restrict__ ald, float* __restrict__ mvec) {
    __shared__ unsigned int hist[256];
    __shared__ unsigned int stmp[256];
    __shared__ unsigned int loc2[256];
    __shared__ unsigned int srcbuf[BCAP];
    int t = threadIdx.x;
    if (blockIdx.x >= nb) {  // mgemm role: second half of nodes
        int mblk = mg1 + (blockIdx.x - nb);
        int m0 = mblk * 128 + (t >> 6) * 16;
        mgemm_wave<128, false>(x, p0h, p0l, asrc, adst, xh16, als, ald, mvec, m0, t & 63, n);
        return;
    }
    int b = blockIdx.x;
    int e0 = boffs[b], e1 = boffs[b + 1];
    int cnt = e1 - e0;
    int pb = e0 + b * PADSLACK;
    if (t < 256) hist[t] = 0;
    __syncthreads();
    for (int j = t; j < cnt; j += 512) atomicAdd(&hist[edata[e0 + j] >> 24], 1u);
    __syncthreads();
    unsigned int v = 0, v4 = 0;
    if (t < 256) {
        v = hist[t];
        v4 = (v + 3u) & ~3u;
        stmp[t] = v4;
    }
    __syncthreads();
    for (int o = 1; o < 256; o <<= 1) {
        unsigned int add = 0;
        if (t < 256 && t >= o) add = stmp[t - o];
        __syncthreads();
        if (t < 256) stmp[t] += add;
        __syncthreads();
    }
    int ptot = (int)stmp[255];
    if (t < 256) {
        loc2[t] = stmp[t] - v4;  // padded exclusive offset
        int node = b * 256 + t;
        if (node < n) {
            poffs[node] = pb + (int)loc2[t];
            pend[node] = pb + (int)(loc2[t] + v4);
        }
        hist[t] = loc2[t];  // cursor
    }
    __syncthreads();
    if (cnt + PADSLACK <= BCAP) {
        for (int j = t; j < cnt; j += 512) {
            unsigned int p = edata[e0 + j];
            unsigned int pos = atomicAdd(&hist[p >> 24], 1u);
            srcbuf[pos] = p & 0xFFFFFFu;
        }
        if (t < 256)
            for (unsigned int k = v; k < v4; ++k) srcbuf[loc2[t] + k] = (unsigned int)n;  // pads
        __syncthreads();
        for (int j = t; j < ptot; j += 512) ssrc[pb + j] = (int)srcbuf[j];
    } else {  // safety fallback (never hit for Poisson(4096) buckets)
        for (int j = t; j < cnt; j += 512) {
            unsigned int p = edata[e0 + j];
            unsigned int pos = atomicAdd(&hist[p >> 24], 1u);
            ssrc[pb + (int)pos] = (int)(p & 0xFFFFFFu);
        }
        if (t < 256)
            for (unsigned int k = v; k < v4; ++k) ssrc[pb + (int)(loc2[t] + k)] = n;
    }
}

__device__ inline float4 lrelu4(float4 v) {
    float4 r;
    r.x = v.x >= 0.f ? v.x : 0.2f * v.x;
    r.y = v.y >= 0.f ? v.y : 0.2f * v.y;
    r.z = v.z >= 0.f ? v.z : 0.2f * v.z;
    r.w = v.w >= 0.f ? v.w : 0.2f * v.w;
    return r;
}

// Aligned accumulate over [LO,HI) within chunk starting at s0; fp16 row
// gathers (128B/edge), two fmac chains per node.
#define ACCUM(LO, HI, ACCA, ACCB, ZS)                                           \
    {                                                                           \
        int g_ = ((LO) - s0) >> 2, gb_ = ((HI) - s0) >> 2;                      \
        for (; g_ + 4 <= gb_; g_ += 4) {                                        \
            int4 uu0 = *(const int4*)&ub[g_ * 4];                               \
            int4 uu1 = *(const int4*)&ub[g_ * 4 + 4];                           \
            int4 uu2 = *(const int4*)&ub[g_ * 4 + 8];                           \
            int4 uu3 = *(const int4*)&ub[g_ * 4 + 12];                          \
            float4 pp0 = *(const float4*)&per[g_ * 4];                          \
            float4 pp1 = *(const float4*)&per[g_ * 4 + 4];                      \
            float4 pp2 = *(const float4*)&per[g_ * 4 + 8];                      \
            float4 pp3 = *(const float4*)&per[g_ * 4 + 12];                     \
            float x0 = (float)*(const half_t*)(xl + (size_t)(unsigned)uu0.x);   \
            float x1 = (float)*(const half_t*)(xl + (size_t)(unsigned)uu0.y);   \
            float x2 = (float)*(const half_t*)(xl + (size_t)(unsigned)uu0.z);   \
            float x3 = (float)*(const half_t*)(xl + (size_t)(unsigned)uu0.w);   \
            float x4 = (float)*(const half_t*)(xl + (size_t)(unsigned)uu1.x);   \
            float x5 = (float)*(const half_t*)(xl + (size_t)(unsigned)uu1.y);   \
            float x6 = (float)*(const half_t*)(xl + (size_t)(unsigned)uu1.z);   \
            float x7 = (float)*(const half_t*)(xl + (size_t)(unsigned)uu1.w);   \
            float x8 = (float)*(const half_t*)(xl + (size_t)(unsigned)uu2.x);   \
            float x9 = (float)*(const half_t*)(xl + (size_t)(unsigned)uu2.y);   \
            float xa = (float)*(const half_t*)(xl + (size_t)(unsigned)uu2.z);   \
            float xb = (float)*(const half_t*)(xl + (size_t)(unsigned)uu2.w);   \
            float xc = (float)*(const half_t*)(xl + (size_t)(unsigned)uu3.x);   \
            float xd = (float)*(const half_t*)(xl + (size_t)(unsigned)uu3.y);   \
            float xe = (float)*(const half_t*)(xl + (size_t)(unsigned)uu3.z);   \
            float xf = (float)*(const half_t*)(xl + (size_t)(unsigned)uu3.w);   \
            ZS += pp0.x + pp0.y + pp0.z + pp0.w;                                \
            ZS += pp1.x + pp1.y + pp1.z + pp1.w;                                \
            ZS += pp2.x + pp2.y + pp2.z + pp2.w;                                \
            ZS += pp3.x + pp3.y + pp3.z + pp3.w;                                \
            ACCA += pp0.x * x0; ACCB += pp0.y * x1;                             \
            ACCA += pp0.z * x2; ACCB += pp0.w * x3;                             \
            ACCA += pp1.x * x4; ACCB += pp1.y * x5;                             \
            ACCA += pp1.z * x6; ACCB += pp1.w * x7;                             \
            ACCA += pp2.x * x8; ACCB += pp2.y * x9;                             \
            ACCA += pp2.z * xa; ACCB += pp2.w * xb;                             \
            ACCA += pp3.x * xc; ACCB += pp3.y * xd;                             \
            ACCA += pp3.z * xe; ACCB += pp3.w * xf;                             \
        }                                                                       \
        for (; g_ < gb_; ++g_) {                                                \
            int4 uu = *(const int4*)&ub[g_ * 4];                                \
            float4 pp = *(const float4*)&per[g_ * 4];                           \
            float x0 = (float)*(const half_t*)(xl + (size_t)(unsigned)uu.x);    \
            float x1 = (float)*(const half_t*)(xl + (size_t)(unsigned)uu.y);    \
            float x2 = (float)*(const half_t*)(xl + (size_t)(unsigned)uu.z);    \
            float x3 = (float)*(const half_t*)(xl + (size_t)(unsigned)uu.w);    \
            ZS += pp.x + pp.y + pp.z + pp.w;                                    \
            ACCA += pp.x * x0; ACCB += pp.y * x1;                               \
            ACCA += pp.z * x2; ACCB += pp.w * x3;                               \
        }                                                                       \
    }

// agg body for one virtual block vb (4 waves x 4 nodes). Same-wave LDS only,
// no __syncthreads -> safe per-wave early return.
__device__ __forceinline__ void agg_body(int vb, const half_t* __restrict__ xh16,
                                         const float* __restrict__ als, const float* __restrict__ ald,
                                         const float* __restrict__ mvec,
                                         const int* __restrict__ poffs, const int* __restrict__ pend,
                                         const int* __restrict__ ssrc,
                                         const float* __restrict__ bias, half_t* __restrict__ hout,
                                         const float* __restrict__ outw, const float* __restrict__ outb,
                                         float* __restrict__ fout, int n) {
    static __shared__ int s_u[4][64];
    static __shared__ float s_pe[4][4][64];  // [wslot][head][edge]
    int wslot = threadIdx.x >> 6;
    int lane = threadIdx.x & 63;
    int v0 = ((vb << 2) + wslot) << 2;
    if (v0 >= n) return;
    int head = lane >> 4;
    int* ub = s_u[wslot];
    float* per = s_pe[wslot][head];      // read row for my head
    float* pew = &s_pe[wslot][0][lane];  // write base, stride 64 per head

    int vlast = n - 1;
    int last = min(v0 + 3, vlast);
    int4 rr = *(const int4*)(poffs + v0);
    int e3 = pend[last];
    int r0 = rr.x;
    int r1 = (v0 + 1 <= last) ? rr.y : e3;
    int r2 = (v0 + 2 <= last) ? rr.z : e3;
    int r3 = (v0 + 3 <= last) ? rr.w : e3;

    const char* xl = (const char*)(xh16 + lane);  // lane column folded into base
    float acc0a = (float)xh16[((size_t)(unsigned)v0 << 6) + lane];  // self, pe=1
    float acc1a = (float)xh16[((size_t)(unsigned)min(v0 + 1, vlast) << 6) + lane];
    float acc2a = (float)xh16[((size_t)(unsigned)min(v0 + 2, vlast) << 6) + lane];
    float acc3a = (float)xh16[((size_t)(unsigned)min(v0 + 3, vlast) << 6) + lane];
    float acc0b = 0.f, acc1b = 0.f, acc2b = 0.f, acc3b = 0.f;
    float zs0 = 0.f, zs1 = 0.f, zs2 = 0.f, zs3 = 0.f;

    // prefetch chunk 0 (ssrc -> dependent als gather; ald/m by nid)
    int s0 = r0;
    int u_n = n;
    if (s0 < e3) {
        if (lane < e3 - s0) u_n = ssrc[s0 + lane];
    }
    float4 alu_n = *(const float4*)(als + 4 * (size_t)u_n);
    int e_n = s0 + lane;
    int nid_n = min(v0 + (e_n >= r1) + (e_n >= r2) + (e_n >= r3), vlast);
    float4 ald_n = *(const float4*)(ald + 4 * (size_t)nid_n);
    float4 m_n = *(const float4*)(mvec + 4 * (size_t)nid_n);

    while (s0 < e3) {
        int cnt = min(64, e3 - s0);
        float4 e4 = lrelu4(make_float4(alu_n.x + ald_n.x, alu_n.y + ald_n.y,
                                       alu_n.z + ald_n.z, alu_n.w + ald_n.w));
        float4 pe;
        pe.x = __expf(e4.x - m_n.x);
        pe.y = __expf(e4.y - m_n.y);
        pe.z = __expf(e4.z - m_n.z);
        pe.w = __expf(e4.w - m_n.w);
        ub[lane] = u_n << 7;  // fp16 row byte offset; pads point at phantom n
        pew[0] = pe.x;        // transposed stash: bank stride 64 -> 2-way, free
        pew[64] = pe.y;
        pew[128] = pe.z;
        pew[192] = pe.w;
        int s1 = s0 + 64;
        if (s1 < e3) {  // issue next chunk's loads before accumulate
            u_n = n;
            if (lane < e3 - s1) u_n = ssrc[s1 + lane];
            alu_n = *(const float4*)(als + 4 * (size_t)u_n);
            int e1 = s1 + lane;
            int nid1 = min(v0 + (e1 >= r1) + (e1 >= r2) + (e1 >= r3), vlast);
            ald_n = *(const float4*)(ald + 4 * (size_t)nid1);
            m_n = *(const float4*)(mvec + 4 * (size_t)nid1);
        }
        // same-wave LDS RAW (in-order DS unit), no barrier needed
        int lim = s0 + cnt;
        int hi0 = min(r1, lim);
        int lo1 = max(r1, s0), hi1 = min(r2, lim);
        int lo2 = max(r2, s0), hi2 = min(r3, lim);
        int lo3 = max(r3, s0);
        ACCUM(s0, hi0, acc0a, acc0b, zs0);
        ACCUM(lo1, hi1, acc1a, acc1b, zs1);
        ACCUM(lo2, hi2, acc2a, acc2b, zs2);
        ACCUM(lo3, lim, acc3a, acc3b, zs3);
        s0 = s1;
    }

    float bl = bias[lane];
    float o0 = fmaxf((acc0a + acc0b) / (1.f + zs0 + 1e-16f) + bl, 0.f);
    float o1 = fmaxf((acc1a + acc1b) / (1.f + zs1 + 1e-16f) + bl, 0.f);
    float o2 = fmaxf((acc2a + acc2b) / (1.f + zs2 + 1e-16f) + bl, 0.f);
    float o3 = fmaxf((acc3a + acc3b) / (1.f + zs3 + 1e-16f) + bl, 0.f);
    if (outw) {
        float ow = outw[lane];
        float ob = outb[0];
        float t0 = o0 * ow, t1 = o1 * ow, t2 = o2 * ow, t3 = o3 * ow;
#pragma unroll
        for (int d = 32; d; d >>= 1) {
            t0 += __shfl_down(t0, d, 64);
            t1 += __shfl_down(t1, d, 64);
            t2 += __shfl_down(t2, d, 64);
            t3 += __shfl_down(t3, d, 64);
        }
        if (lane == 0) {
            fout[v0] = t0 + ob;
            if (v0 + 1 < n) fout[v0 + 1] = t1 + ob;
            if (v0 + 2 < n) fout[v0 + 2] = t2 + ob;
            if (v0 + 3 < n) fout[v0 + 3] = t3 + ob;
        }
    } else {
        hout[((size_t)v0 << 6) + lane] = (half_t)o0;
        if (v0 + 1 < n) hout[((size_t)(v0 + 1) << 6) + lane] = (half_t)o1;
        if (v0 + 2 < n) hout[((size_t)(v0 + 2) << 6) + lane] = (half_t)o2;
        if (v0 + 3 < n) hout[((size_t)(v0 + 3) << 6) + lane] = (half_t)o3;
    }
}

// Hand-rolled grid barrier (R12 fix): RELAXED spin + s_sleep backoff; one
// threadfence before the signal (release) and one after spin exit (acquire).
// All TGRID blocks resident (launch_bounds cap) -> no deadlock. Monotonic
// targets survive dispatch replay (counter re-zeroed by k_prep each launch).
__device__ __forceinline__ void grid_barrier(int* cnt, int phase) {
    __syncthreads();
    if (threadIdx.x == 0) {
        __threadfence();  // release: publish this block's writes
        __hip_atomic_fetch_add(cnt, 1, __ATOMIC_RELAXED, __HIP_MEMORY_SCOPE_AGENT);
        int target = TGRID * (phase + 1);
        while (__hip_atomic_load(cnt, __ATOMIC_RELAXED, __HIP_MEMORY_SCOPE_AGENT) < target)
            __builtin_amdgcn_s_sleep(32);
        __threadfence();  // acquire: invalidate stale per-XCD lines ONCE
    }
    __syncthreads();
}

// ---- fused tail: agg0 -> mgemm64(L1) -> agg1 -> mgemm64(L2) -> agg2+head.
// Regular launch (graph-capture-safe). 1024 blocks, all resident.
__global__ __launch_bounds__(256, 4) void k_tail(const half_t* xh16, half_t* hbuf,
                                                 float* als, float* ald, float* mvec,
                                                 const int* poffs, const int* pend, const int* ssrc,
                                                 const float* b0, const float* b1, const float* b2,
                                                 const unsigned short* p1h, const unsigned short* p1l,
                                                 const unsigned short* p2h, const unsigned short* p2l,
                                                 const float* as1, const float* ad1,
                                                 const float* as2, const float* ad2,
                                                 const float* outw, const float* outb,
                                                 float* fout, int* gbar, int n) {
    int nvb = (n + 15) / 16;   // agg virtual blocks
    int ngb = (n + 63) / 64;   // mgemm64 virtual blocks
    int t = threadIdx.x;

    // phase 0: agg layer 0 (xh16 -> hbuf)
    for (int vb = blockIdx.x; vb < nvb; vb += gridDim.x)
        agg_body(vb, xh16, als, ald, mvec, poffs, pend, ssrc, b0, hbuf, nullptr, nullptr, nullptr, n);
    grid_barrier(gbar, 0);
    // phase 1: mgemm64 layer 1 (hbuf -> xh16, als/ald/mvec)
    for (int mb = blockIdx.x; mb < ngb; mb += gridDim.x)
        mgemm_wave<64, true>(hbuf, p1h, p1l, as1, ad1, (half_t*)xh16, als, ald, mvec,
                             mb * 64 + (t >> 6) * 16, t & 63, n);
    grid_barrier(gbar, 1);
    // phase 2: agg layer 1 (xh16 -> hbuf)
    for (int vb = blockIdx.x; vb < nvb; vb += gridDim.x)
        agg_body(vb, xh16, als, ald, mvec, poffs, pend, ssrc, b1, hbuf, nullptr, nullptr, nullptr, n);
    grid_barrier(gbar, 2);
    // phase 3: mgemm64 layer 2
    for (int mb = blockIdx.x; mb < ngb; mb += gridDim.x)
        mgemm_wave<64, true>(hbuf, p2h, p2l, as2, ad2, (half_t*)xh16, als, ald, mvec,
                             mb * 64 + (t >> 6) * 16, t & 63, n);
    grid_barrier(gbar, 3);
    // phase 4: agg layer 2 + fused linear head
    for (int vb = blockIdx.x; vb < nvb; vb += gridDim.x)
        agg_body(vb, xh16, als, ald, mvec, poffs, pend, ssrc, b2, nullptr, outw, outb, fout, n);
}

extern "C" void kernel_launch(void* const* d_in, const int* in_sizes, int n_in,
                              void* d_out, int out_size, void* d_ws, size_t ws_size,
                              hipStream_t stream) {
    const float* x = (const float*)d_in[0];
    const int* ei = (const int*)d_in[1];
    const float* w[3] = {(const float*)d_in[2], (const float*)d_in[6], (const float*)d_in[10]};
    const float* as[3] = {(const float*)d_in[3], (const float*)d_in[7], (const float*)d_in[11]};
    const float* ad[3] = {(const float*)d_in[4], (const float*)d_in[8], (const float*)d_in[12]};
    const float* b[3] = {(const float*)d_in[5], (const float*)d_in[9], (const float*)d_in[13]};
    const float* outw = (const float*)d_in[14];
    const float* outb = (const float*)d_in[15];

    const int N = in_sizes[0] / 128;
    const int E = in_sizes[1] / 2;
    const int* src = ei;
    const int* dst = ei + E;
    const int NB = (N + 255) / 256;           // 391 <= NBMAX
    const int SB = (E + SCHUNK - 1) / SCHUNK; // 391
    const int GB128 = (N + 127) / 128;        // 782
    const int MG1 = (GB128 + 1) / 2;          // 391
    const int MG2 = GB128 - MG1;              // 391

    char* ws = (char*)d_ws;
    auto alloc = [&](size_t bytes) -> void* {
        void* p = (void*)ws;
        ws += (bytes + 255) & ~(size_t)255;
        return p;
    };
    int* bhist = (int*)alloc(NBMAX * 4);
    int* boffs = (int*)alloc((NBMAX + 1) * 4);
    int* bfill = (int*)alloc(NBMAX * 4);
    int* gbar = (int*)alloc(256);
    int* poffs = (int*)alloc((size_t)(N + 8) * 4);
    int* pend = (int*)alloc((size_t)N * 4);
    int* ssrc = (int*)alloc((size_t)(E + NBMAX * PADSLACK + 256) * 4);
    half_t* xh16 = (half_t*)alloc((size_t)(N + 1) * 64 * 2);  // +1: phantom zero row
    half_t* hbuf = (half_t*)alloc((size_t)N * 64 * 2);
    float* als = (float*)alloc((size_t)(N + 1) * 4 * 4);  // +1: phantom -1e30
    float* ald = (float*)alloc((size_t)N * 4 * 4);
    float* mvec = (float*)alloc((size_t)N * 4 * 4);
    unsigned short* p0h = (unsigned short*)alloc(8192 * 2);
    unsigned short* p0l = (unsigned short*)alloc(8192 * 2);
    unsigned short* p1h = (unsigned short*)alloc(4096 * 2);
    unsigned short* p1l = (unsigned short*)alloc(4096 * 2);
    unsigned short* p2h = (unsigned short*)alloc(4096 * 2);
    unsigned short* p2l = (unsigned short*)alloc(4096 * 2);
    // edata (E*4B = 6.4MB) aliases hbuf (N*128B = 12.8MB): hbuf stays dead
    // until k_tail phase 0 writes it, after k_mix2 consumed edata.
    unsigned int* edata = (unsigned int*)hbuf;

    hipMemsetAsync(bhist, 0, NBMAX * 4, stream);  // stream-ordered; capture-safe
    k_prep<<<9 + NBH, 256, 0, stream>>>(w[0], w[1], w[2], p0h, p0l, p1h, p1l, p2h, p2l,
                                        bhist, dst, E, als, xh16, gbar, N);
    k_bscan<<<1, 512, 0, stream>>>(bhist, boffs, bfill, NB, E);
    // CSR scatter || layer-0 GEMM first half (independent workloads)
    k_mix1<<<SB + MG1, 512, 0, stream>>>(src, dst, boffs, bfill, edata, E, SB,
                                         x, p0h, p0l, as[0], ad[0], xh16, als, ald, mvec, N);
    // CSR finalize || layer-0 GEMM second half
    k_mix2<<<NB + MG2, 512, 0, stream>>>(edata, boffs, poffs, pend, ssrc, N, NB, MG1,
                                         x, p0h, p0l, as[0], ad[0], xh16, als, ald, mvec);
    // fused tail: agg0 -> mg1 -> agg1 -> mg2 -> agg2+head (one regular launch)
    k_tail<<<TGRID, 256, 0, stream>>>(xh16, hbuf, als, ald, mvec, poffs, pend, ssrc,
                                      b[0], b[1], b[2], p1h, p1l, p2h, p2l,
                                      as[1], ad[1], as[2], ad[2],
                                      outw, outb, (float*)d_out, gbar, N);
}

// Round 14
// 363.831 us; speedup vs baseline: 3.0673x; 2.4371x over previous
//
#include <hip/hip_runtime.h>

// GAT node regressor: 3 GAT layers (HID=64, 4 heads x 16) + linear head.
// CSR-by-dst via bucketed counting sort, per-node ranges PADDED to x4 (pads
// -> phantom node n: als[n]=-1e30 so pe==0; fp16 xh row n zeroed).
// Node features between layers stored ONCE, in fp16 (exact bf16 hi/lo
// re-split on GEMM input; single rounding event per layer): gathers
// 128B/row, GEMM A-reads and inter-layer stores halved vs fp32. k_agg
// gather path is the measured floor (54us, 115MB, latency-bound: VALU 51%,
// HBM 27%, no pipe saturated). Layer-0 GEMM (MFMA bf16 hi/lo from fp32 x)
// overlapped with CSR build via k_mix1/k_mix2. bhist fused into k_prep
// (zeroed by hipMemsetAsync).
// R11-R13 NEGATIVE RESULT (kept for the record): fusing the tail chain into
// one kernel with a grid barrier is structurally unprofitable on 8-XCD
// CDNA4 — cross-XCD visibility at each barrier forces per-phase L2
// writeback+invalidate (WRITE 0.4->88MB, phases 3-4x slower). Kernel-
// boundary flushes are cheaper than any software barrier here.

#define NBMAX 512    // max dst buckets (dst>>8); N=100K -> 391
#define SCHUNK 4096  // edges per bscatter block
#define BCAP 8192    // per-bucket LDS capacity in bfinal (avg 4096+pads)
#define PADSLACK 768 // max padding per bucket = 256 nodes * 3 slots
#define NBH 256      // bhist role blocks inside k_prep

typedef __attribute__((ext_vector_type(8))) short bf16x8;
typedef __attribute__((ext_vector_type(4))) float f32x4;
typedef _Float16 half_t;
typedef __attribute__((ext_vector_type(8))) _Float16 half8;

__device__ inline unsigned short bf16_rtn(float x) {
    union { float f; unsigned u; } a; a.f = x;
    return (unsigned short)((a.u + 0x7FFFu + ((a.u >> 16) & 1u)) >> 16);
}
__device__ inline float bf16_to_f(unsigned short s) {
    union { unsigned u; float f; } b; b.u = ((unsigned)s) << 16;
    return b.f;
}

// ---- fused W-prep + phantom init + dst histogram (bhist pre-zeroed by
// hipMemsetAsync): blocks 0-7 wprep, 8 init, 9..9+NBH-1 bhist ----
__global__ __launch_bounds__(256) void k_prep(const float* __restrict__ w0, const float* __restrict__ w1,
                                              const float* __restrict__ w2,
                                              unsigned short* __restrict__ p0h, unsigned short* __restrict__ p0l,
                                              unsigned short* __restrict__ p1h, unsigned short* __restrict__ p1l,
                                              unsigned short* __restrict__ p2h, unsigned short* __restrict__ p2l,
                                              int* __restrict__ bhist, const int* __restrict__ dst, int e,
                                              float* __restrict__ als, half_t* __restrict__ xh16, int n) {
    __shared__ unsigned int h[NBMAX];
    int bid = blockIdx.x, t = threadIdx.x;
    if (bid == 8) {  // phantom node init
        if (t < 4) als[(size_t)n * 4 + t] = -1e30f;
        if (t < 64) xh16[(size_t)n * 64 + t] = (half_t)0.f;
        return;
    }
    if (bid >= 9) {  // bhist role (bhist already zeroed via memset)
        int bb = bid - 9;
        h[t] = 0;
        h[t + 256] = 0;
        __syncthreads();
        for (int i = bb * 256 + t; i < e; i += NBH * 256)
            atomicAdd(&h[dst[i] >> 8], 1u);
        __syncthreads();
        if (h[t]) atomicAdd(&bhist[t], (int)h[t]);
        if (h[t + 256]) atomicAdd(&bhist[t + 256], (int)h[t + 256]);
        return;
    }
    int g = bid * 256 + t;
    const float* W;
    unsigned short *ph, *pl;
    int idx;
    if (g < 1024) { W = w0; ph = p0h; pl = p0l; idx = g; }          // D=128: ko 0..15
    else if (g < 1536) { W = w1; ph = p1h; pl = p1l; idx = g - 1024; }  // D=64: ko 0..7
    else if (g < 2048) { W = w2; ph = p2h; pl = p2l; idx = g - 1536; }
    else return;
    int ko = idx >> 6, nn = idx & 63;
#pragma unroll
    for (int j = 0; j < 8; ++j) {
        float w = W[(size_t)(ko * 8 + j) * 64 + nn];
        unsigned short hb = bf16_rtn(w);
        ph[(size_t)idx * 8 + j] = hb;
        pl[(size_t)idx * 8 + j] = bf16_rtn(w - bf16_to_f(hb));
    }
}

__global__ __launch_bounds__(512) void k_bscan(const int* __restrict__ bhist, int* __restrict__ boffs,
                                               int* __restrict__ bfill, int nb, int e) {
    __shared__ int s[NBMAX];
    int t = threadIdx.x;
    int v = (t < nb) ? bhist[t] : 0;
    s[t] = v;
    __syncthreads();
    for (int o = 1; o < 512; o <<= 1) {
        int add = (t >= o) ? s[t - o] : 0;
        __syncthreads();
        s[t] += add;
        __syncthreads();
    }
    boffs[t] = s[t] - v;  // exclusive
    if (t == 511) boffs[512] = s[511];
    bfill[t] = 0;
}

// ---- mgemm wave body: 16 nodes x 64 cols, fused logits + softmax shift.
// HALF_IN: A rows are fp16 (exact under bf16 hi/lo re-split). Writes only
// the fp16 feature copy + fp32 logits (from the unrounded MFMA acc). ----
template <int D_IN, bool HALF_IN>
__device__ __forceinline__ void mgemm_wave(const void* __restrict__ hv,
                                           const unsigned short* __restrict__ wph,
                                           const unsigned short* __restrict__ wpl,
                                           const float* __restrict__ asrc, const float* __restrict__ adst,
                                           half_t* __restrict__ xh16, float* __restrict__ als,
                                           float* __restrict__ ald, float* __restrict__ mvec,
                                           int m0, int lane, int n) {
    int quad = lane >> 4, l16 = lane & 15;
    int node_a = m0 + l16;
    int mm = min(node_a, n - 1);

    f32x4 acc[4];
#pragma unroll
    for (int i = 0; i < 4; ++i) acc[i] = (f32x4){0.f, 0.f, 0.f, 0.f};

    constexpr int KSTEPS = D_IN / 32;
#pragma unroll
    for (int s = 0; s < KSTEPS; ++s) {
        float av[8];
        if constexpr (HALF_IN) {
            const half_t* hrow = (const half_t*)hv + (size_t)mm * D_IN + quad * 8;
            half8 hvv = *(const half8*)(hrow + s * 32);
#pragma unroll
            for (int j = 0; j < 8; ++j) av[j] = (float)hvv[j];
        } else {
            const float* hrow = (const float*)hv + (size_t)mm * D_IN + quad * 8;
            float4 a0 = *(const float4*)(hrow + s * 32);
            float4 a1 = *(const float4*)(hrow + s * 32 + 4);
            av[0] = a0.x; av[1] = a0.y; av[2] = a0.z; av[3] = a0.w;
            av[4] = a1.x; av[5] = a1.y; av[6] = a1.z; av[7] = a1.w;
        }
        bf16x8 ahi, alo;
#pragma unroll
        for (int j = 0; j < 8; ++j) {
            unsigned short hb = bf16_rtn(av[j]);
            ahi[j] = (short)hb;
            alo[j] = (short)bf16_rtn(av[j] - bf16_to_f(hb));
        }
        const unsigned short* bbase = wph + ((size_t)((s * 4 + quad) * 64 + l16)) * 8;
        const unsigned short* bbasel = wpl + ((size_t)((s * 4 + quad) * 64 + l16)) * 8;
#pragma unroll
        for (int nt = 0; nt < 4; ++nt) {
            bf16x8 bhi = *(const bf16x8*)(bbase + (size_t)nt * 16 * 8);
            bf16x8 blo = *(const bf16x8*)(bbasel + (size_t)nt * 16 * 8);
            acc[nt] = __builtin_amdgcn_mfma_f32_16x16x32_bf16(ahi, bhi, acc[nt], 0, 0, 0);
            acc[nt] = __builtin_amdgcn_mfma_f32_16x16x32_bf16(ahi, blo, acc[nt], 0, 0, 0);
            acc[nt] = __builtin_amdgcn_mfma_f32_16x16x32_bf16(alo, bhi, acc[nt], 0, 0, 0);
        }
    }
#pragma unroll
    for (int nt = 0; nt < 4; ++nt) {
        float as_l = asrc[nt * 16 + l16];
        float ad_l = adst[nt * 16 + l16];
#pragma unroll
        for (int r = 0; r < 4; ++r) {
            int node = m0 + quad * 4 + r;
            float c = acc[nt][r];
            if (node < n) xh16[(size_t)node * 64 + nt * 16 + l16] = (half_t)c;
            float ps = c * as_l, pd = c * ad_l;
            ps += __shfl_xor(ps, 1, 64); pd += __shfl_xor(pd, 1, 64);
            ps += __shfl_xor(ps, 2, 64); pd += __shfl_xor(pd, 2, 64);
            ps += __shfl_xor(ps, 4, 64); pd += __shfl_xor(pd, 4, 64);
            ps += __shfl_xor(ps, 8, 64); pd += __shfl_xor(pd, 8, 64);
            if (l16 == 0 && node < n) {
                als[node * 4 + nt] = ps;
                ald[node * 4 + nt] = pd;
                float sm = ps + pd;
                mvec[node * 4 + nt] = sm >= 0.f ? sm : 0.2f * sm;
            }
        }
    }
}

// Standalone mgemm for layers 1-2 (D=64, fp16 input): 4 waves x 16 nodes.
__global__ __launch_bounds__(256) void k_mgemm64(const half_t* __restrict__ h,
                                                 const unsigned short* __restrict__ wph,
                                                 const unsigned short* __restrict__ wpl,
                                                 const float* __restrict__ asrc, const float* __restrict__ adst,
                                                 half_t* __restrict__ xh16, float* __restrict__ als,
                                                 float* __restrict__ ald, float* __restrict__ mvec, int n) {
    int t = threadIdx.x;
    int m0 = blockIdx.x * 64 + (t >> 6) * 16;
    mgemm_wave<64, true>(h, wph, wpl, asrc, adst, xh16, als, ald, mvec, m0, t & 63, n);
}

// ---- k_mix1: bscatter (blocks [0,sb)) || layer-0 GEMM half 1 (8 waves) ----
__global__ __launch_bounds__(512) void k_mix1(const int* __restrict__ src, const int* __restrict__ dst,
                                              const int* __restrict__ boffs, int* __restrict__ bfill,
                                              unsigned int* __restrict__ edata, int e, int sb,
                                              const float* __restrict__ x,
                                              const unsigned short* __restrict__ p0h,
                                              const unsigned short* __restrict__ p0l,
                                              const float* __restrict__ asrc, const float* __restrict__ adst,
                                              half_t* __restrict__ xh16, float* __restrict__ als,
                                              float* __restrict__ ald, float* __restrict__ mvec, int n) {
    __shared__ unsigned int hist[NBMAX];
    __shared__ unsigned int loc[NBMAX];
    __shared__ int gbase[NBMAX];
    __shared__ unsigned int stmp[NBMAX];
    __shared__ unsigned int sortbuf[SCHUNK];
    __shared__ int posbuf[SCHUNK];
    int t = threadIdx.x;
    if (blockIdx.x >= sb) {  // mgemm role
        int mblk = blockIdx.x - sb;
        int m0 = mblk * 128 + (t >> 6) * 16;
        mgemm_wave<128, false>(x, p0h, p0l, asrc, adst, xh16, als, ald, mvec, m0, t & 63, n);
        return;
    }
    int i0 = blockIdx.x * SCHUNK;
    int cnt = min(SCHUNK, e - i0);
    hist[t] = 0;
    __syncthreads();
    for (int j = t; j < cnt; j += 512) atomicAdd(&hist[dst[i0 + j] >> 8], 1u);
    __syncthreads();
    unsigned int v = hist[t];
    stmp[t] = v;
    __syncthreads();
    for (int o = 1; o < 512; o <<= 1) {
        unsigned int add = (t >= o) ? stmp[t - o] : 0;
        __syncthreads();
        stmp[t] += add;
        __syncthreads();
    }
    loc[t] = stmp[t] - v;
    int gb = 0;
    if (v > 0) gb = atomicAdd(&bfill[t], (int)v);  // reserve contiguous run in bucket t
    gbase[t] = boffs[t] + gb - (int)loc[t];
    hist[t] = loc[t];  // cursor
    __syncthreads();
    for (int j = t; j < cnt; j += 512) {
        int d = dst[i0 + j];
        int s = src[i0 + j];
        int b = d >> 8;
        unsigned int p = atomicAdd(&hist[b], 1u);
        sortbuf[p] = (unsigned int)s | ((unsigned int)(d & 255) << 24);
        posbuf[p] = gbase[b] + (int)p;
    }
    __syncthreads();
    for (int j = t; j < cnt; j += 512) edata[posbuf[j]] = sortbuf[j];
}

// ---- k_mix2: bfinal (blocks [0,nb)) || layer-0 GEMM half 2 ----
__global__ __launch_bounds__(512) void k_mix2(const unsigned int* __restrict__ edata,
                                              const int* __restrict__ boffs, int* __restrict__ poffs,
                                              int* __restrict__ pend, int* __restrict__ ssrc,
                                              int n, int nb, int mg1,
                                              const float* __restrict__ x,
                                              const unsigned short* __restrict__ p0h,
                                              const unsigned short* __restrict__ p0l,
                                              const float* __restrict__ asrc, const float* __restrict__ adst,
                                              half_t* __restrict__ xh16, float* __restrict__ als,
                                              float* __restrict__ ald, float* __restrict__ mvec) {
    __shared__ unsigned int hist[256];
    __shared__ unsigned int stmp[256];
    __shared__ unsigned int loc2[256];
    __shared__ unsigned int srcbuf[BCAP];
    int t = threadIdx.x;
    if (blockIdx.x >= nb) {  // mgemm role: second half of nodes
        int mblk = mg1 + (blockIdx.x - nb);
        int m0 = mblk * 128 + (t >> 6) * 16;
        mgemm_wave<128, false>(x, p0h, p0l, asrc, adst, xh16, als, ald, mvec, m0, t & 63, n);
        return;
    }
    int b = blockIdx.x;
    int e0 = boffs[b], e1 = boffs[b + 1];
    int cnt = e1 - e0;
    int pb = e0 + b * PADSLACK;
    if (t < 256) hist[t] = 0;
    __syncthreads();
    for (int j = t; j < cnt; j += 512) atomicAdd(&hist[edata[e0 + j] >> 24], 1u);
    __syncthreads();
    unsigned int v = 0, v4 = 0;
    if (t < 256) {
        v = hist[t];
        v4 = (v + 3u) & ~3u;
        stmp[t] = v4;
    }
    __syncthreads();
    for (int o = 1; o < 256; o <<= 1) {
        unsigned int add = 0;
        if (t < 256 && t >= o) add = stmp[t - o];
        __syncthreads();
        if (t < 256) stmp[t] += add;
        __syncthreads();
    }
    int ptot = (int)stmp[255];
    if (t < 256) {
        loc2[t] = stmp[t] - v4;  // padded exclusive offset
        int node = b * 256 + t;
        if (node < n) {
            poffs[node] = pb + (int)loc2[t];
            pend[node] = pb + (int)(loc2[t] + v4);
        }
        hist[t] = loc2[t];  // cursor
    }
    __syncthreads();
    if (cnt + PADSLACK <= BCAP) {
        for (int j = t; j < cnt; j += 512) {
            unsigned int p = edata[e0 + j];
            unsigned int pos = atomicAdd(&hist[p >> 24], 1u);
            srcbuf[pos] = p & 0xFFFFFFu;
        }
        if (t < 256)
            for (unsigned int k = v; k < v4; ++k) srcbuf[loc2[t] + k] = (unsigned int)n;  // pads
        __syncthreads();
        for (int j = t; j < ptot; j += 512) ssrc[pb + j] = (int)srcbuf[j];
    } else {  // safety fallback (never hit for Poisson(4096) buckets)
        for (int j = t; j < cnt; j += 512) {
            unsigned int p = edata[e0 + j];
            unsigned int pos = atomicAdd(&hist[p >> 24], 1u);
            ssrc[pb + (int)pos] = (int)(p & 0xFFFFFFu);
        }
        if (t < 256)
            for (unsigned int k = v; k < v4; ++k) ssrc[pb + (int)(loc2[t] + k)] = n;
    }
}

__device__ inline float4 lrelu4(float4 v) {
    float4 r;
    r.x = v.x >= 0.f ? v.x : 0.2f * v.x;
    r.y = v.y >= 0.f ? v.y : 0.2f * v.y;
    r.z = v.z >= 0.f ? v.z : 0.2f * v.z;
    r.w = v.w >= 0.f ? v.w : 0.2f * v.w;
    return r;
}

// Aligned accumulate over [LO,HI) within chunk starting at s0; fp16 row
// gathers (128B/edge), two fmac chains per node.
#define ACCUM(LO, HI, ACCA, ACCB, ZS)                                           \
    {                                                                           \
        int g_ = ((LO) - s0) >> 2, gb_ = ((HI) - s0) >> 2;                      \
        for (; g_ + 4 <= gb_; g_ += 4) {                                        \
            int4 uu0 = *(const int4*)&ub[g_ * 4];                               \
            int4 uu1 = *(const int4*)&ub[g_ * 4 + 4];                           \
            int4 uu2 = *(const int4*)&ub[g_ * 4 + 8];                           \
            int4 uu3 = *(const int4*)&ub[g_ * 4 + 12];                          \
            float4 pp0 = *(const float4*)&per[g_ * 4];                          \
            float4 pp1 = *(const float4*)&per[g_ * 4 + 4];                      \
            float4 pp2 = *(const float4*)&per[g_ * 4 + 8];                      \
            float4 pp3 = *(const float4*)&per[g_ * 4 + 12];                     \
            float x0 = (float)*(const half_t*)(xl + (size_t)(unsigned)uu0.x);   \
            float x1 = (float)*(const half_t*)(xl + (size_t)(unsigned)uu0.y);   \
            float x2 = (float)*(const half_t*)(xl + (size_t)(unsigned)uu0.z);   \
            float x3 = (float)*(const half_t*)(xl + (size_t)(unsigned)uu0.w);   \
            float x4 = (float)*(const half_t*)(xl + (size_t)(unsigned)uu1.x);   \
            float x5 = (float)*(const half_t*)(xl + (size_t)(unsigned)uu1.y);   \
            float x6 = (float)*(const half_t*)(xl + (size_t)(unsigned)uu1.z);   \
            float x7 = (float)*(const half_t*)(xl + (size_t)(unsigned)uu1.w);   \
            float x8 = (float)*(const half_t*)(xl + (size_t)(unsigned)uu2.x);   \
            float x9 = (float)*(const half_t*)(xl + (size_t)(unsigned)uu2.y);   \
            float xa = (float)*(const half_t*)(xl + (size_t)(unsigned)uu2.z);   \
            float xb = (float)*(const half_t*)(xl + (size_t)(unsigned)uu2.w);   \
            float xc = (float)*(const half_t*)(xl + (size_t)(unsigned)uu3.x);   \
            float xd = (float)*(const half_t*)(xl + (size_t)(unsigned)uu3.y);   \
            float xe = (float)*(const half_t*)(xl + (size_t)(unsigned)uu3.z);   \
            float xf = (float)*(const half_t*)(xl + (size_t)(unsigned)uu3.w);   \
            ZS += pp0.x + pp0.y + pp0.z + pp0.w;                                \
            ZS += pp1.x + pp1.y + pp1.z + pp1.w;                                \
            ZS += pp2.x + pp2.y + pp2.z + pp2.w;                                \
            ZS += pp3.x + pp3.y + pp3.z + pp3.w;                                \
            ACCA += pp0.x * x0; ACCB += pp0.y * x1;                             \
            ACCA += pp0.z * x2; ACCB += pp0.w * x3;                             \
            ACCA += pp1.x * x4; ACCB += pp1.y * x5;                             \
            ACCA += pp1.z * x6; ACCB += pp1.w * x7;                             \
            ACCA += pp2.x * x8; ACCB += pp2.y * x9;                             \
            ACCA += pp2.z * xa; ACCB += pp2.w * xb;                             \
            ACCA += pp3.x * xc; ACCB += pp3.y * xd;                             \
            ACCA += pp3.z * xe; ACCB += pp3.w * xf;                             \
        }                                                                       \
        for (; g_ < gb_; ++g_) {                                                \
            int4 uu = *(const int4*)&ub[g_ * 4];                                \
            float4 pp = *(const float4*)&per[g_ * 4];                           \
            float x0 = (float)*(const half_t*)(xl + (size_t)(unsigned)uu.x);    \
            float x1 = (float)*(const half_t*)(xl + (size_t)(unsigned)uu.y);    \
            float x2 = (float)*(const half_t*)(xl + (size_t)(unsigned)uu.z);    \
            float x3 = (float)*(const half_t*)(xl + (size_t)(unsigned)uu.w);    \
            ZS += pp.x + pp.y + pp.z + pp.w;                                    \
            ACCA += pp.x * x0; ACCB += pp.y * x1;                               \
            ACCA += pp.z * x2; ACCB += pp.w * x3;                               \
        }                                                                       \
    }

__global__ __launch_bounds__(256) void k_agg(const half_t* __restrict__ xh16,
                                             const float* __restrict__ als, const float* __restrict__ ald,
                                             const float* __restrict__ mvec,
                                             const int* __restrict__ poffs, const int* __restrict__ pend,
                                             const int* __restrict__ ssrc,
                                             const float* __restrict__ bias, half_t* __restrict__ hout,
                                             const float* __restrict__ outw, const float* __restrict__ outb,
                                             float* __restrict__ fout, int n) {
    __shared__ int s_u[4][64];
    __shared__ float s_pe[4][4][64];  // [wslot][head][edge]
    int wslot = threadIdx.x >> 6;
    int lane = threadIdx.x & 63;
    int w = (blockIdx.x * 256 + threadIdx.x) >> 6;
    int v0 = w << 2;
    if (v0 >= n) return;
    int head = lane >> 4;
    int* ub = s_u[wslot];
    float* per = s_pe[wslot][head];      // read row for my head
    float* pew = &s_pe[wslot][0][lane];  // write base, stride 64 per head

    int vlast = n - 1;
    int last = min(v0 + 3, vlast);
    int4 rr = *(const int4*)(poffs + v0);
    int e3 = pend[last];
    int r0 = rr.x;
    int r1 = (v0 + 1 <= last) ? rr.y : e3;
    int r2 = (v0 + 2 <= last) ? rr.z : e3;
    int r3 = (v0 + 3 <= last) ? rr.w : e3;

    const char* xl = (const char*)(xh16 + lane);  // lane column folded into base
    // self edges (pe = 1), fp16 feature copy
    float acc0a = (float)xh16[((size_t)(unsigned)v0 << 6) + lane];
    float acc1a = (float)xh16[((size_t)(unsigned)min(v0 + 1, vlast) << 6) + lane];
    float acc2a = (float)xh16[((size_t)(unsigned)min(v0 + 2, vlast) << 6) + lane];
    float acc3a = (float)xh16[((size_t)(unsigned)min(v0 + 3, vlast) << 6) + lane];
    float acc0b = 0.f, acc1b = 0.f, acc2b = 0.f, acc3b = 0.f;
    float zs0 = 0.f, zs1 = 0.f, zs2 = 0.f, zs3 = 0.f;

    // prefetch chunk 0 (ssrc -> dependent als gather; ald/m by nid)
    int s0 = r0;
    int u_n = n;
    if (s0 < e3) {
        if (lane < e3 - s0) u_n = ssrc[s0 + lane];
    }
    float4 alu_n = *(const float4*)(als + 4 * (size_t)u_n);
    int e_n = s0 + lane;
    int nid_n = min(v0 + (e_n >= r1) + (e_n >= r2) + (e_n >= r3), vlast);
    float4 ald_n = *(const float4*)(ald + 4 * (size_t)nid_n);
    float4 m_n = *(const float4*)(mvec + 4 * (size_t)nid_n);

    while (s0 < e3) {
        int cnt = min(64, e3 - s0);
        float4 e4 = lrelu4(make_float4(alu_n.x + ald_n.x, alu_n.y + ald_n.y,
                                       alu_n.z + ald_n.z, alu_n.w + ald_n.w));
        float4 pe;
        pe.x = __expf(e4.x - m_n.x);
        pe.y = __expf(e4.y - m_n.y);
        pe.z = __expf(e4.z - m_n.z);
        pe.w = __expf(e4.w - m_n.w);
        ub[lane] = u_n << 7;  // fp16 row byte offset; pads point at phantom n
        pew[0] = pe.x;        // transposed stash: bank stride 64 -> 2-way, free
        pew[64] = pe.y;
        pew[128] = pe.z;
        pew[192] = pe.w;
        int s1 = s0 + 64;
        if (s1 < e3) {  // issue next chunk's loads before accumulate
            u_n = n;
            if (lane < e3 - s1) u_n = ssrc[s1 + lane];
            alu_n = *(const float4*)(als + 4 * (size_t)u_n);
            int e1 = s1 + lane;
            int nid1 = min(v0 + (e1 >= r1) + (e1 >= r2) + (e1 >= r3), vlast);
            ald_n = *(const float4*)(ald + 4 * (size_t)nid1);
            m_n = *(const float4*)(mvec + 4 * (size_t)nid1);
        }
        // same-wave LDS RAW (in-order DS unit), no barrier needed
        int lim = s0 + cnt;
        int hi0 = min(r1, lim);
        int lo1 = max(r1, s0), hi1 = min(r2, lim);
        int lo2 = max(r2, s0), hi2 = min(r3, lim);
        int lo3 = max(r3, s0);
        ACCUM(s0, hi0, acc0a, acc0b, zs0);
        ACCUM(lo1, hi1, acc1a, acc1b, zs1);
        ACCUM(lo2, hi2, acc2a, acc2b, zs2);
        ACCUM(lo3, lim, acc3a, acc3b, zs3);
        s0 = s1;
    }

    float bl = bias[lane];
    float o0 = fmaxf((acc0a + acc0b) / (1.f + zs0 + 1e-16f) + bl, 0.f);
    float o1 = fmaxf((acc1a + acc1b) / (1.f + zs1 + 1e-16f) + bl, 0.f);
    float o2 = fmaxf((acc2a + acc2b) / (1.f + zs2 + 1e-16f) + bl, 0.f);
    float o3 = fmaxf((acc3a + acc3b) / (1.f + zs3 + 1e-16f) + bl, 0.f);
    if (outw) {
        float ow = outw[lane];
        float ob = outb[0];
        float t0 = o0 * ow, t1 = o1 * ow, t2 = o2 * ow, t3 = o3 * ow;
#pragma unroll
        for (int d = 32; d; d >>= 1) {
            t0 += __shfl_down(t0, d, 64);
            t1 += __shfl_down(t1, d, 64);
            t2 += __shfl_down(t2, d, 64);
            t3 += __shfl_down(t3, d, 64);
        }
        if (lane == 0) {
            fout[v0] = t0 + ob;
            if (v0 + 1 < n) fout[v0 + 1] = t1 + ob;
            if (v0 + 2 < n) fout[v0 + 2] = t2 + ob;
            if (v0 + 3 < n) fout[v0 + 3] = t3 + ob;
        }
    } else {
        hout[((size_t)v0 << 6) + lane] = (half_t)o0;
        if (v0 + 1 < n) hout[((size_t)(v0 + 1) << 6) + lane] = (half_t)o1;
        if (v0 + 2 < n) hout[((size_t)(v0 + 2) << 6) + lane] = (half_t)o2;
        if (v0 + 3 < n) hout[((size_t)(v0 + 3) << 6) + lane] = (half_t)o3;
    }
}

extern "C" void kernel_launch(void* const* d_in, const int* in_sizes, int n_in,
                              void* d_out, int out_size, void* d_ws, size_t ws_size,
                              hipStream_t stream) {
    const float* x = (const float*)d_in[0];
    const int* ei = (const int*)d_in[1];
    const float* w[3] = {(const float*)d_in[2], (const float*)d_in[6], (const float*)d_in[10]};
    const float* as[3] = {(const float*)d_in[3], (const float*)d_in[7], (const float*)d_in[11]};
    const float* ad[3] = {(const float*)d_in[4], (const float*)d_in[8], (const float*)d_in[12]};
    const float* b[3] = {(const float*)d_in[5], (const float*)d_in[9], (const float*)d_in[13]};
    const float* outw = (const float*)d_in[14];
    const float* outb = (const float*)d_in[15];

    const int N = in_sizes[0] / 128;
    const int E = in_sizes[1] / 2;
    const int* src = ei;
    const int* dst = ei + E;
    const int NB = (N + 255) / 256;           // 391 <= NBMAX
    const int SB = (E + SCHUNK - 1) / SCHUNK; // 391
    const int GB128 = (N + 127) / 128;        // 782
    const int MG1 = (GB128 + 1) / 2;          // 391
    const int MG2 = GB128 - MG1;              // 391

    char* ws = (char*)d_ws;
    auto alloc = [&](size_t bytes) -> void* {
        void* p = (void*)ws;
        ws += (bytes + 255) & ~(size_t)255;
        return p;
    };
    int* bhist = (int*)alloc(NBMAX * 4);
    int* boffs = (int*)alloc((NBMAX + 1) * 4);
    int* bfill = (int*)alloc(NBMAX * 4);
    int* poffs = (int*)alloc((size_t)(N + 8) * 4);
    int* pend = (int*)alloc((size_t)N * 4);
    int* ssrc = (int*)alloc((size_t)(E + NBMAX * PADSLACK + 256) * 4);
    half_t* xh16 = (half_t*)alloc((size_t)(N + 1) * 64 * 2);  // +1: phantom zero row
    half_t* hbuf = (half_t*)alloc((size_t)N * 64 * 2);
    float* als = (float*)alloc((size_t)(N + 1) * 4 * 4);  // +1: phantom -1e30
    float* ald = (float*)alloc((size_t)N * 4 * 4);
    float* mvec = (float*)alloc((size_t)N * 4 * 4);
    unsigned short* p0h = (unsigned short*)alloc(8192 * 2);
    unsigned short* p0l = (unsigned short*)alloc(8192 * 2);
    unsigned short* p1h = (unsigned short*)alloc(4096 * 2);
    unsigned short* p1l = (unsigned short*)alloc(4096 * 2);
    unsigned short* p2h = (unsigned short*)alloc(4096 * 2);
    unsigned short* p2l = (unsigned short*)alloc(4096 * 2);
    // edata (E*4B = 6.4MB) aliases hbuf (N*128B = 12.8MB): hbuf stays dead
    // until agg0 writes it, which is after k_mix2 consumed edata.
    unsigned int* edata = (unsigned int*)hbuf;

    hipMemsetAsync(bhist, 0, NBMAX * 4, stream);  // stream-ordered; graph-capture-safe
    k_prep<<<9 + NBH, 256, 0, stream>>>(w[0], w[1], w[2], p0h, p0l, p1h, p1l, p2h, p2l,
                                        bhist, dst, E, als, xh16, N);
    k_bscan<<<1, 512, 0, stream>>>(bhist, boffs, bfill, NB, E);
    // CSR scatter || layer-0 GEMM first half (independent workloads)
    k_mix1<<<SB + MG1, 512, 0, stream>>>(src, dst, boffs, bfill, edata, E, SB,
                                         x, p0h, p0l, as[0], ad[0], xh16, als, ald, mvec, N);
    // CSR finalize || layer-0 GEMM second half
    k_mix2<<<NB + MG2, 512, 0, stream>>>(edata, boffs, poffs, pend, ssrc, N, NB, MG1,
                                         x, p0h, p0l, as[0], ad[0], xh16, als, ald, mvec);

    const int gblocks = (N + 63) / 64;
    const int ablocks = (N + 15) / 16;  // 4 nodes/wave, 4 waves/block

    k_agg<<<ablocks, 256, 0, stream>>>(xh16, als, ald, mvec, poffs, pend, ssrc, b[0], hbuf, nullptr, nullptr, nullptr, N);
    k_mgemm64<<<gblocks, 256, 0, stream>>>(hbuf, p1h, p1l, as[1], ad[1], xh16, als, ald, mvec, N);
    k_agg<<<ablocks, 256, 0, stream>>>(xh16, als, ald, mvec, poffs, pend, ssrc, b[1], hbuf, nullptr, nullptr, nullptr, N);
    k_mgemm64<<<gblocks, 256, 0, stream>>>(hbuf, p2h, p2l, as[2], ad[2], xh16, als, ald, mvec, N);
    k_agg<<<ablocks, 256, 0, stream>>>(xh16, als, ald, mvec, poffs, pend, ssrc, b[2], nullptr, outw, outb, (float*)d_out, N);
}